// Round 11
// baseline (575.786 us; speedup 1.0000x reference)
//
#include <hip/hip_runtime.h>

// Problem constants (B,S,E,H,DK,DV,DF) = (4,2048,512,8,64,64,2048)
#define Bx  4
#define Sx  2048
#define Ex  512
#define Hx  8
#define Tt  (Bx * Sx)          // 8192 tokens

typedef short          short8 __attribute__((ext_vector_type(8)));  // 8 bf16
typedef float          f32x4  __attribute__((ext_vector_type(4)));  // MFMA C/D
typedef unsigned short u16;

__device__ __forceinline__ u16 f2bf(float f) {
    unsigned int u = __float_as_uint(f);
    u += 0x7fffu + ((u >> 16) & 1u);          // round-to-nearest-even
    return (u16)(u >> 16);
}
__device__ __forceinline__ float bf2f(u16 h) {
    return __uint_as_float(((unsigned int)h) << 16);
}
// packed f32x2 -> bf16x2, RNE (bit-identical to f2bf); S0 -> [15:0], S1 -> [31:16]
__device__ __forceinline__ unsigned int cvt_pk_bf16(float lo, float hi) {
    unsigned int r;
    asm("v_cvt_pk_bf16_f32 %0, %1, %2" : "=v"(r) : "v"(lo), "v"(hi));
    return r;
}
// async global->LDS, 16B per lane. LDS dest is WAVE-UNIFORM base + lane*16
// (m104/m108); global source is per-lane. size must be a literal.
typedef const __attribute__((address_space(1))) void* gas1_t;
typedef __attribute__((address_space(3))) void*       las3_t;
__device__ __forceinline__ void gload16(const u16* g, u16* l) {
    __builtin_amdgcn_global_load_lds((gas1_t)g, (las3_t)l, 16, 0, 0);
}

struct WPtrs { const float* w[8]; };

// ---------------------------------------------------------------------------
// prepass: ALL pre-work in ONE dispatch (v10). flat block id ranges:
//   [0,4096) x->bf16 | [4096,8192) enc->bf16 | [8192,10240) 8x 512^2 W^T
//   [10240,11264) ff_W1^T | [11264,12288) ff_W2^T
// ---------------------------------------------------------------------------
struct PreArgs {
    const float* x; const float* enc; u16* xb; u16* encb;
    WPtrs wp; u16* bw;
    const float* ffW1; u16* wff1;
    const float* ffW2; u16* wff2;
};
__global__ __launch_bounds__(256) void prepass(PreArgs a)
{
    __shared__ u16 tile[32][33];
    const int bid = blockIdx.x;
    const int tid = threadIdx.x;

    if (bid < 8192) {
        const float* in  = bid < 4096 ? a.x : a.enc;
        u16*         out = bid < 4096 ? a.xb : a.encb;
        const int bb = bid < 4096 ? bid : bid - 4096;
        const int i  = (bb * 256 + tid) << 2;
        float4 v = *(const float4*)(in + i);
        ushort4 o;
        o.x = f2bf(v.x); o.y = f2bf(v.y); o.z = f2bf(v.z); o.w = f2bf(v.w);
        *(ushort4*)(out + i) = o;
        return;
    }
    const float* W; u16* Wt; int K, N, bx, by;
    if (bid < 10240) {
        const int wi = bid - 8192, slot = wi >> 8, r = wi & 255;
        W = a.wp.w[slot]; Wt = a.bw + (size_t)slot * 262144;
        K = 512; N = 512; bx = r & 15; by = r >> 4;
    } else if (bid < 11264) {
        const int wi = bid - 10240;
        W = a.ffW1; Wt = a.wff1; K = 512; N = 2048; bx = wi & 63; by = wi >> 6;
    } else {
        const int wi = bid - 11264;
        W = a.ffW2; Wt = a.wff2; K = 2048; N = 512; bx = wi & 15; by = wi >> 4;
    }
    const int n0 = bx * 32, k0 = by * 32;
    const int tx = tid & 31, ty = tid >> 5;
#pragma unroll
    for (int i = 0; i < 32; i += 8)
        tile[ty + i][tx] = f2bf(W[(size_t)(k0 + ty + i) * N + n0 + tx]);
    __syncthreads();
#pragma unroll
    for (int i = 0; i < 32; i += 8)
        Wt[(size_t)(n0 + ty + i) * K + k0 + tx] = tile[tx][ty + i];
}

// ---------------------------------------------------------------------------
// gemm128 v2: 128x128 tile, BK=32, 256 thr = 4 waves (2x2), wave 64x64.
//   Staging via global_load_lds width=16 (m97 recipe). (unchanged)
// ---------------------------------------------------------------------------
template<int OUT_BF16, int RELU>
__global__ __launch_bounds__(256) void gemm128(const u16* __restrict__ A,
                                               const u16* __restrict__ Bt,
                                               const float* __restrict__ b0,
                                               const float* __restrict__ b1,
                                               const float* __restrict__ b2,
                                               const float* __restrict__ b3,
                                               void* __restrict__ Cout,
                                               int M, int N, int K, int ldc)
{
    __shared__ u16 As[128 * 32];
    __shared__ u16 Bs[128 * 32];

    const int tid  = threadIdx.x;
    const int w    = tid >> 6;
    const int lane = tid & 63;
    const int c    = lane & 15;
    const int quad = lane >> 4;
    const int wr   = w >> 1, wc = w & 1;
    const int m0   = blockIdx.y * 128;
    const int n0   = blockIdx.x * 128;

    const int srow = lane >> 2;
    const int scol = (lane & 3) << 3;
    const u16* Ag0 = A  + (size_t)(m0 + w * 32 + srow) * K + scol;
    const u16* Ag1 = Ag0 + (size_t)16 * K;
    const u16* Bg0 = Bt + (size_t)(n0 + w * 32 + srow) * K + scol;
    const u16* Bg1 = Bg0 + (size_t)16 * K;
    u16* AsB0 = &As[(w * 2 + 0) * 512];
    u16* AsB1 = &As[(w * 2 + 1) * 512];
    u16* BsB0 = &Bs[(w * 2 + 0) * 512];
    u16* BsB1 = &Bs[(w * 2 + 1) * 512];

    f32x4 acc[4][4];
#pragma unroll
    for (int i = 0; i < 4; i++)
#pragma unroll
        for (int j = 0; j < 4; j++) { acc[i][j][0]=0.f; acc[i][j][1]=0.f; acc[i][j][2]=0.f; acc[i][j][3]=0.f; }

    for (int k0 = 0; k0 < K; k0 += 32) {
        __syncthreads();
        gload16(Ag0 + k0, AsB0);
        gload16(Ag1 + k0, AsB1);
        gload16(Bg0 + k0, BsB0);
        gload16(Bg1 + k0, BsB1);
        __syncthreads();

        short8 af[4], bf[4];
#pragma unroll
        for (int i = 0; i < 4; i++)
            af[i] = *(const short8*)&As[(wr * 64 + i * 16 + c) * 32 + quad * 8];
#pragma unroll
        for (int j = 0; j < 4; j++)
            bf[j] = *(const short8*)&Bs[(wc * 64 + j * 16 + c) * 32 + quad * 8];
#pragma unroll
        for (int i = 0; i < 4; i++)
#pragma unroll
            for (int j = 0; j < 4; j++)
                acc[i][j] = __builtin_amdgcn_mfma_f32_16x16x32_bf16(af[i], bf[j], acc[i][j], 0, 0, 0);
    }

    const int seg = n0 >> 9;
    const float* bp = seg == 0 ? b0 : (seg == 1 ? b1 : (seg == 2 ? b2 : b3));
    const int nbase = n0 & 511;
    float bv[4];
#pragma unroll
    for (int j = 0; j < 4; j++) bv[j] = bp[nbase + wc * 64 + j * 16 + c];

#pragma unroll
    for (int i = 0; i < 4; i++) {
#pragma unroll
        for (int j = 0; j < 4; j++) {
            int colg = n0 + wc * 64 + j * 16 + c;
#pragma unroll
            for (int r = 0; r < 4; r++) {
                int rowg = m0 + wr * 64 + i * 16 + quad * 4 + r;
                float v = acc[i][j][r] + bv[j];
                if (RELU) v = fmaxf(v, 0.f);
                if (OUT_BF16) ((u16*)Cout)[(size_t)rowg * ldc + colg] = f2bf(v);
                else          ((float*)Cout)[(size_t)rowg * ldc + colg] = v;
            }
        }
    }
}

// ---------------------------------------------------------------------------
// gemm128_dual (v10): QKV (12 N-blocks) + caKV (8 N-blocks) in ONE launch.
//   (unchanged)
// ---------------------------------------------------------------------------
struct DualArgs {
    const u16* A0; const u16* B0; u16* C0;          // QKV
    const float* qb0; const float* qb1; const float* qb2;
    const u16* A1; const u16* B1; u16* C1;          // caKV
    const float* cb0; const float* cb1;
};
__global__ __launch_bounds__(256) void gemm128_dual(DualArgs d)
{
    __shared__ u16 As[128 * 32];
    __shared__ u16 Bs[128 * 32];

    const int tid  = threadIdx.x;
    const int w    = tid >> 6;
    const int lane = tid & 63;
    const int c    = lane & 15;
    const int quad = lane >> 4;
    const int wr   = w >> 1, wc = w & 1;
    const int m0   = blockIdx.y * 128;

    const u16* A; const u16* Bt; u16* C; int ldc, n0; const float* bp;
    if ((int)blockIdx.x < 12) {
        A = d.A0; Bt = d.B0; C = d.C0; ldc = 1536; n0 = blockIdx.x * 128;
        const int seg = n0 >> 9;
        bp = seg == 0 ? d.qb0 : (seg == 1 ? d.qb1 : d.qb2);
    } else {
        A = d.A1; Bt = d.B1; C = d.C1; ldc = 1024; n0 = (blockIdx.x - 12) * 128;
        bp = (n0 >> 9) ? d.cb1 : d.cb0;
    }
    const int K = 512;

    const int srow = lane >> 2;
    const int scol = (lane & 3) << 3;
    const u16* Ag0 = A  + (size_t)(m0 + w * 32 + srow) * K + scol;
    const u16* Ag1 = Ag0 + (size_t)16 * K;
    const u16* Bg0 = Bt + (size_t)(n0 + w * 32 + srow) * K + scol;
    const u16* Bg1 = Bg0 + (size_t)16 * K;
    u16* AsB0 = &As[(w * 2 + 0) * 512];
    u16* AsB1 = &As[(w * 2 + 1) * 512];
    u16* BsB0 = &Bs[(w * 2 + 0) * 512];
    u16* BsB1 = &Bs[(w * 2 + 1) * 512];

    f32x4 acc[4][4];
#pragma unroll
    for (int i = 0; i < 4; i++)
#pragma unroll
        for (int j = 0; j < 4; j++) { acc[i][j][0]=0.f; acc[i][j][1]=0.f; acc[i][j][2]=0.f; acc[i][j][3]=0.f; }

    for (int k0 = 0; k0 < K; k0 += 32) {
        __syncthreads();
        gload16(Ag0 + k0, AsB0);
        gload16(Ag1 + k0, AsB1);
        gload16(Bg0 + k0, BsB0);
        gload16(Bg1 + k0, BsB1);
        __syncthreads();

        short8 af[4], bf[4];
#pragma unroll
        for (int i = 0; i < 4; i++)
            af[i] = *(const short8*)&As[(wr * 64 + i * 16 + c) * 32 + quad * 8];
#pragma unroll
        for (int j = 0; j < 4; j++)
            bf[j] = *(const short8*)&Bs[(wc * 64 + j * 16 + c) * 32 + quad * 8];
#pragma unroll
        for (int i = 0; i < 4; i++)
#pragma unroll
            for (int j = 0; j < 4; j++)
                acc[i][j] = __builtin_amdgcn_mfma_f32_16x16x32_bf16(af[i], bf[j], acc[i][j], 0, 0, 0);
    }

    const int nbase = n0 & 511;
    float bv[4];
#pragma unroll
    for (int j = 0; j < 4; j++) bv[j] = bp[nbase + wc * 64 + j * 16 + c];

#pragma unroll
    for (int i = 0; i < 4; i++) {
#pragma unroll
        for (int j = 0; j < 4; j++) {
            int colg = n0 + wc * 64 + j * 16 + c;
#pragma unroll
            for (int r = 0; r < 4; r++) {
                int rowg = m0 + wr * 64 + i * 16 + quad * 4 + r;
                C[(size_t)rowg * ldc + colg] = f2bf(acc[i][j][r] + bv[j]);
            }
        }
    }
}

// ---------------------------------------------------------------------------
// gemm64 v2: 128x64 tile, BK=32, 256 thr = 4 waves, direct-to-LDS staging.
//   (unchanged)
// ---------------------------------------------------------------------------
template<int OUT_BF16, int RELU>
__global__ __launch_bounds__(256) void gemm64(const u16* __restrict__ A,
                                              const u16* __restrict__ Bt,
                                              const float* __restrict__ bias,
                                              void* __restrict__ Cout,
                                              int M, int N, int K, int ldc)
{
    __shared__ u16 As[128 * 32];
    __shared__ u16 Bs[64 * 32];

    const int tid  = threadIdx.x;
    const int w    = tid >> 6;          // 0..3
    const int lane = tid & 63;
    const int c    = lane & 15;
    const int quad = lane >> 4;
    const int m0   = blockIdx.y * 128;
    const int n0   = blockIdx.x * 64;

    const int srow = lane >> 2;
    const int scol = (lane & 3) << 3;
    const u16* Ag0 = A  + (size_t)(m0 + w * 32 + srow) * K + scol;
    const u16* Ag1 = Ag0 + (size_t)16 * K;
    const u16* Bg  = Bt + (size_t)(n0 + w * 16 + srow) * K + scol;
    u16* AsB0 = &As[(w * 2 + 0) * 512];
    u16* AsB1 = &As[(w * 2 + 1) * 512];
    u16* BsB  = &Bs[w * 512];

    f32x4 acc[2][4];
#pragma unroll
    for (int i = 0; i < 2; i++)
#pragma unroll
        for (int j = 0; j < 4; j++) { acc[i][j][0]=0.f; acc[i][j][1]=0.f; acc[i][j][2]=0.f; acc[i][j][3]=0.f; }

    for (int k0 = 0; k0 < K; k0 += 32) {
        __syncthreads();
        gload16(Ag0 + k0, AsB0);
        gload16(Ag1 + k0, AsB1);
        gload16(Bg  + k0, BsB);
        __syncthreads();

        short8 af[2], bf[4];
#pragma unroll
        for (int i = 0; i < 2; i++)
            af[i] = *(const short8*)&As[(w * 32 + i * 16 + c) * 32 + quad * 8];
#pragma unroll
        for (int j = 0; j < 4; j++)
            bf[j] = *(const short8*)&Bs[(j * 16 + c) * 32 + quad * 8];
#pragma unroll
        for (int i = 0; i < 2; i++)
#pragma unroll
            for (int j = 0; j < 4; j++)
                acc[i][j] = __builtin_amdgcn_mfma_f32_16x16x32_bf16(af[i], bf[j], acc[i][j], 0, 0, 0);
    }

    float bv[4];
#pragma unroll
    for (int j = 0; j < 4; j++) bv[j] = bias[n0 + j * 16 + c];

#pragma unroll
    for (int i = 0; i < 2; i++) {
#pragma unroll
        for (int j = 0; j < 4; j++) {
            int colg = n0 + j * 16 + c;
#pragma unroll
            for (int r = 0; r < 4; r++) {
                int rowg = m0 + w * 32 + i * 16 + quad * 4 + r;
                float v = acc[i][j][r] + bv[j];
                if (RELU) v = fmaxf(v, 0.f);
                if (OUT_BF16) ((u16*)Cout)[(size_t)rowg * ldc + colg] = f2bf(v);
                else          ((float*)Cout)[(size_t)rowg * ldc + colg] = v;
            }
        }
    }
}

// ---------------------------------------------------------------------------
// MFMA flash attention v11: K DIRECT FROM L2 INTO REGISTERS (no K LDS).
//   v10 counters: LDS ~33%, VALU 29%, MFMA 8.5% -- critical-path-bound.
//   K/V slices are L2-resident (256KB per bh; XCD swizzle keeps 4 bh = 2MB
//   per XCD's 4MB L2), so K staging through LDS was pure overhead (guide
//   common-mistake #7; m169 +26%). Each wave consumes the WHOLE K-tile as
//   per-lane frags (row f*16+c, col quad*8) -- exactly a per-lane global
//   load. v11 prefetches K-frags one tile ahead into REGISTERS (8 b128
//   L2-hit loads, double-buffered kfA/kfB, loop unrolled 2 tiles -> all
//   static register indexing, rule #20). kend is always a multiple of 128
//   (cross: 2048; causal: q0+128), so tiles pair exactly.
//   V keeps the LDS sigma-transpose path (one barrier/tile, V-only now:
//   LDS ops/thread/tile 20 -> 10 b128; post-barrier kb-read chain gone).
//   K loads never OOB (rows < kend <= Sx), so no causal guards on loads.
//   Rest unchanged: swapped QK^T (P in regs), 32 q/wave, cvt_pk pack,
//   XCD swizzle, 72-u16 V strides.
// Layouts (m89/m91): A[m=lane&15][k=quad*8+j], B[k=quad*8+j][n=lane&15],
// C/D: col=lane&15, row=quad*4+reg. sigma(slot): qs=slot>>3, j=slot&7,
// key = (j<4 ? qs*4+j : 16+qs*4+j-4) (+32 second half); applied to both
// P-pack (A) and V^T staging (B) so it cancels.
// ---------------------------------------------------------------------------
template<bool CAUSAL>
__device__ __forceinline__ void attn_tile(
    int kt, int kend, int qw, int c, int quad,
    const u16* Kb, const u16* Vgp, int ldk, int ldv,
    const int (&vkey)[8], int vdim, int vp,
    const u16* VtC, u16* VtN,
    const short8 (&qa)[2][2],
    short8 (&KC)[4][2], short8 (&KN)[4][2],
    f32x4 (&of)[2][4], float (&lpart)[2])
{
    const bool more = (kt + 64 < kend);

    // ---- prefetch next tile: K -> registers, V -> registers ----
    union { short8 v; u16 u[8]; } vb0, vb1;
    if (more) {
        const size_t kn = kt + 64;
#pragma unroll
        for (int f = 0; f < 4; f++) {
            KN[f][0] = *(const short8*)(Kb + (kn + f * 16) * (size_t)ldk);
            KN[f][1] = *(const short8*)(Kb + (kn + f * 16) * (size_t)ldk + 32);
        }
#pragma unroll
        for (int j = 0; j < 8; j++) vb0.u[j] = Vgp[(kn + vkey[j]) * (size_t)ldv];
#pragma unroll
        for (int j = 0; j < 8; j++) vb1.u[j] = Vgp[(kn + 32 + vkey[j]) * (size_t)ldv];
    }

    int fm0 = 4, fm1 = 4;                    // live 16-key frags per q-frag
    if (CAUSAL) {
        int d0 = ((qw + 15 - kt) >> 4) + 1;  // arithmetic shift: can be <=0
        int d1 = ((qw + 31 - kt) >> 4) + 1;
        fm0 = d0 < 0 ? 0 : (d0 > 4 ? 4 : d0);
        fm1 = d1 < 0 ? 0 : (d1 > 4 ? 4 : d1);   // fm1 >= fm0
    }

    if (fm1 > 0) {
        // ---- S^T = K Q^T; K frags straight from registers ----
        f32x4 s[2][4];
#pragma unroll
        for (int f = 0; f < 4; f++) {
            if (f < fm1) {
#pragma unroll
                for (int a = 0; a < 2; a++) {
                    const int fma_ = a ? fm1 : fm0;
                    if (f < fma_) {
                        f32x4 z; z[0]=0.f; z[1]=0.f; z[2]=0.f; z[3]=0.f;
                        z = __builtin_amdgcn_mfma_f32_16x16x32_bf16(KC[f][0], qa[a][0], z, 0, 0, 0);
                        z = __builtin_amdgcn_mfma_f32_16x16x32_bf16(KC[f][1], qa[a][1], z, 0, 0, 0);
                        s[a][f] = z;
                    }
                }
            }
        }

        // ---- P = exp(S/8) in-lane; cvt_pk pack; accumulate denom ----
        union { unsigned int u[4]; short8 s8; } paA[2], paB[2];
#pragma unroll
        for (int a = 0; a < 2; a++) {
            const int fma_ = a ? fm1 : fm0;
            const int qg = qw + a * 16 + c;
#pragma unroll
            for (int f = 0; f < 4; f++) {
                float p[4];
#pragma unroll
                for (int r = 0; r < 4; r++) {
                    float pv = 0.f;
                    int kg = kt + f * 16 + quad * 4 + r;
                    if (f < fma_ && !(CAUSAL && kg > qg))
                        pv = __expf(s[a][f][r] * 0.125f);
                    p[r] = pv;
                }
                unsigned int w0 = cvt_pk_bf16(p[0], p[1]);
                unsigned int w1 = cvt_pk_bf16(p[2], p[3]);
                lpart[a] += __uint_as_float(w0 << 16) + __uint_as_float(w0 & 0xffff0000u);
                lpart[a] += __uint_as_float(w1 << 16) + __uint_as_float(w1 & 0xffff0000u);
                if (f < 2) { paA[a].u[f * 2] = w0; paA[a].u[f * 2 + 1] = w1; }
                else       { paB[a].u[(f - 2) * 2] = w0; paB[a].u[(f - 2) * 2 + 1] = w1; }
            }
        }

        // ---- O += P * V; vb reads shared across both q-frags ----
#pragma unroll
        for (int f2 = 0; f2 < 4; f2++) {
            short8 vb0f = *(const short8*)&VtC[(f2 * 16 + c) * 72 + quad * 8];
            short8 vb1f = *(const short8*)&VtC[(f2 * 16 + c) * 72 + 32 + quad * 8];
            if (fm0 > 0)
                of[0][f2] = __builtin_amdgcn_mfma_f32_16x16x32_bf16(paA[0].s8, vb0f, of[0][f2], 0, 0, 0);
            of[1][f2] = __builtin_amdgcn_mfma_f32_16x16x32_bf16(paA[1].s8, vb0f, of[1][f2], 0, 0, 0);
            if (fm0 > 2)
                of[0][f2] = __builtin_amdgcn_mfma_f32_16x16x32_bf16(paB[0].s8, vb1f, of[0][f2], 0, 0, 0);
            if (fm1 > 2)
                of[1][f2] = __builtin_amdgcn_mfma_f32_16x16x32_bf16(paB[1].s8, vb1f, of[1][f2], 0, 0, 0);
        }
    }

    // ---- stage next V tile into the other buffer ----
    if (more) {
        *(short8*)&VtN[vdim * 72 + vp]      = vb0.v;
        *(short8*)&VtN[vdim * 72 + 32 + vp] = vb1.v;
    }
    __syncthreads();                         // RAW(next V) + WAR(cur V)
}

template<bool CAUSAL>
__global__ __launch_bounds__(256) void attn_mfma(const u16* __restrict__ Q,
                                                 const u16* __restrict__ K,
                                                 const u16* __restrict__ V,
                                                 u16* __restrict__ O,
                                                 int ldq, int ldk, int ldv)
{
    __shared__ u16 Vtlds[2][64 * 72];      // [buf][dim][sigma-slot], V only

    const int tid  = threadIdx.x;
    const int w    = tid >> 6;
    const int lane = tid & 63;
    const int c    = lane & 15;
    const int quad = lane >> 4;

    // XCD-aware swizzle; grid (16, 32) = 512 blocks = 8 XCDs * 64.
    const int flat = blockIdx.y * 16 + blockIdx.x;
    const int idx  = flat >> 3;
    const int bh   = (flat & 7) * 4 + (idx >> 4);
    const int q0   = (idx & 15) * 128;

    const int b    = bh >> 3;
    const int h    = bh & 7;
    const int bS   = b * Sx;
    const int hoff = h * 64;
    const int qw   = q0 + w * 32;

    // V staging: thread owns dim tid&63, sigma-slots vp..vp+7 (+32)
    const int vdim = tid & 63;
    const int vq   = tid >> 6;
    const int vp   = vq << 3;
    int vkey[8];
#pragma unroll
    for (int j = 0; j < 8; j++) vkey[j] = ((j & 4) << 2) + (vq << 2) + (j & 3);

    short8 qa[2][2];
#pragma unroll
    for (int a = 0; a < 2; a++) {
        const u16* qp = Q + (size_t)(bS + qw + a * 16 + c) * ldq + hoff;
        qa[a][0] = *(const short8*)(qp + quad * 8);
        qa[a][1] = *(const short8*)(qp + 32 + quad * 8);
    }

    f32x4 of[2][4];
#pragma unroll
    for (int a = 0; a < 2; a++)
#pragma unroll
        for (int f = 0; f < 4; f++) { of[a][f][0]=0.f; of[a][f][1]=0.f; of[a][f][2]=0.f; of[a][f][3]=0.f; }
    float lpart[2] = {0.f, 0.f};

    const int kend = CAUSAL ? (q0 + 128) : Sx;   // always a multiple of 128

    // per-lane K base: row c, col quad*8; frag (f,half) at +((kt+f*16)*ldk + half*32)
    const u16* Kb  = K + (size_t)(bS + c) * ldk + hoff + quad * 8;
    const u16* Vgp = V + (size_t)bS * ldv + hoff + vdim;

    short8 kfA[4][2], kfB[4][2];

    // ---- prologue: tile 0 K -> kfA, V -> LDS buf0 ----
#pragma unroll
    for (int f = 0; f < 4; f++) {
        kfA[f][0] = *(const short8*)(Kb + (size_t)(f * 16) * ldk);
        kfA[f][1] = *(const short8*)(Kb + (size_t)(f * 16) * ldk + 32);
    }
    {
        union { short8 v; u16 u[8]; } vb0, vb1;
#pragma unroll
        for (int j = 0; j < 8; j++) vb0.u[j] = Vgp[(size_t)vkey[j] * ldv];
#pragma unroll
        for (int j = 0; j < 8; j++) vb1.u[j] = Vgp[(size_t)(32 + vkey[j]) * ldv];
        *(short8*)&Vtlds[0][vdim * 72 + vp]      = vb0.v;
        *(short8*)&Vtlds[0][vdim * 72 + 32 + vp] = vb1.v;
    }
    __syncthreads();

    // ---- main loop: 2 tiles per iteration (static reg double-buffer) ----
    for (int kt = 0; kt < kend; kt += 128) {
        attn_tile<CAUSAL>(kt, kend, qw, c, quad, Kb, Vgp, ldk, ldv,
                          vkey, vdim, vp, &Vtlds[0][0], &Vtlds[1][0],
                          qa, kfA, kfB, of, lpart);
        attn_tile<CAUSAL>(kt + 64, kend, qw, c, quad, Kb, Vgp, ldk, ldv,
                          vkey, vdim, vp, &Vtlds[1][0], &Vtlds[0][0],
                          qa, kfB, kfA, of, lpart);
    }

    // ---- denominators: D[query] via xor16/32, then per-row fetch ----
    float rinv[2][4];
#pragma unroll
    for (int a = 0; a < 2; a++) {
        float D = lpart[a];
        D += __shfl_xor(D, 16, 64);
        D += __shfl_xor(D, 32, 64);
        float rcp = 1.f / D;
#pragma unroll
        for (int r = 0; r < 4; r++)
            rinv[a][r] = __shfl(rcp, quad * 4 + r, 64);
    }

    // ---- write O (bf16, stride 512): row = a*16+quad*4+r, col = f*16+c ----
    u16* Ob = O + (size_t)(bS + qw) * Ex + hoff;
#pragma unroll
    for (int a = 0; a < 2; a++)
#pragma unroll
        for (int f = 0; f < 4; f++)
#pragma unroll
            for (int r = 0; r < 4; r++)
                Ob[(size_t)(a * 16 + quad * 4 + r) * Ex + f * 16 + c] =
                    f2bf(of[a][f][r] * rinv[a][r]);
}

// ---------------------------------------------------------------------------
// Fused residual-add + LayerNorm: one wave per row, 4 rows/block. (unchanged)
// ---------------------------------------------------------------------------
__global__ __launch_bounds__(256) void ln_add(const float* __restrict__ x,
                                              const float* __restrict__ s,
                                              const float* __restrict__ g,
                                              const float* __restrict__ bta,
                                              float* __restrict__ out,
                                              u16* __restrict__ out_bf)
{
    const int t    = threadIdx.x;
    const int w    = t >> 6;
    const int lane = t & 63;
    const int row  = blockIdx.x * 4 + w;
    const size_t base = (size_t)row * Ex + lane * 8;
    const int    gi   = lane * 8;

    float4 xv0 = *(const float4*)(x + base);
    float4 xv1 = *(const float4*)(x + base + 4);
    float4 sv0 = *(const float4*)(s + base);
    float4 sv1 = *(const float4*)(s + base + 4);
    float y[8] = { xv0.x + sv0.x, xv0.y + sv0.y, xv0.z + sv0.z, xv0.w + sv0.w,
                   xv1.x + sv1.x, xv1.y + sv1.y, xv1.z + sv1.z, xv1.w + sv1.w };

    float sum = 0.f, sq = 0.f;
#pragma unroll
    for (int i = 0; i < 8; i++) { sum += y[i]; sq += y[i] * y[i]; }
#pragma unroll
    for (int o = 1; o < 64; o <<= 1) {
        sum += __shfl_xor(sum, o, 64);
        sq  += __shfl_xor(sq,  o, 64);
    }

    const float mean = sum * (1.f / 512.f);
    const float var  = sq * (1.f / 512.f) - mean * mean;
    const float rstd = rsqrtf(var + 1e-3f);

    float4 gv0 = *(const float4*)(g + gi);
    float4 gv1 = *(const float4*)(g + gi + 4);
    float4 bv0 = *(const float4*)(bta + gi);
    float4 bv1 = *(const float4*)(bta + gi + 4);
    float gg[8] = { gv0.x, gv0.y, gv0.z, gv0.w, gv1.x, gv1.y, gv1.z, gv1.w };
    float bb[8] = { bv0.x, bv0.y, bv0.z, bv0.w, bv1.x, bv1.y, bv1.z, bv1.w };

    float o8[8];
#pragma unroll
    for (int i = 0; i < 8; i++) o8[i] = (y[i] - mean) * rstd * gg[i] + bb[i];

    *(float4*)(out + base)     = make_float4(o8[0], o8[1], o8[2], o8[3]);
    *(float4*)(out + base + 4) = make_float4(o8[4], o8[5], o8[6], o8[7]);
    if (out_bf) {
        union { short8 v; u16 u[8]; } ob;
#pragma unroll
        for (int i = 0; i < 8; i++) ob.u[i] = f2bf(o8[i]);
        *(short8*)(out_bf + base) = ob.v;
    }
}

// ---------------------------------------------------------------------------
// Orchestration (12 dispatches, v10 layout). 96 MB workspace (MB offsets):
//   [0,8) bw | [8,16) xb / P3 x2f=[8,24) | [16,24) encb
//   [24,48) qkvB | P2 qb=[24,32) | P3 ff1b=[24,56) | [48,56) ob
//   [56,72) projF | [72,88) x1f | [88,96) x1b/x2b
//   kvB -> d_out scratch (dead until ln3 writes it last).
// ---------------------------------------------------------------------------
extern "C" void kernel_launch(void* const* d_in, const int* in_sizes, int n_in,
                              void* d_out, int out_size, void* d_ws, size_t ws_size,
                              hipStream_t stream)
{
    const float* x     = (const float*)d_in[0];
    const float* enc   = (const float*)d_in[1];
    const float* sa_Wq = (const float*)d_in[4],  *sa_bq = (const float*)d_in[5];
    const float* sa_Wk = (const float*)d_in[6],  *sa_bk = (const float*)d_in[7];
    const float* sa_Wv = (const float*)d_in[8],  *sa_bv = (const float*)d_in[9];
    const float* sa_Wo = (const float*)d_in[10], *sa_bo = (const float*)d_in[11];
    const float* ca_Wq = (const float*)d_in[12], *ca_bq = (const float*)d_in[13];
    const float* ca_Wk = (const float*)d_in[14], *ca_bk = (const float*)d_in[15];
    const float* ca_Wv = (const float*)d_in[16], *ca_bv = (const float*)d_in[17];
    const float* ca_Wo = (const float*)d_in[18], *ca_bo = (const float*)d_in[19];
    const float* ff_W1 = (const float*)d_in[20], *ff_b1 = (const float*)d_in[21];
    const float* ff_W2 = (const float*)d_in[22], *ff_b2 = (const float*)d_in[23];
    const float* ln1_g = (const float*)d_in[24], *ln1_b = (const float*)d_in[25];
    const float* ln2_g = (const float*)d_in[26], *ln2_b = (const float*)d_in[27];
    const float* ln3_g = (const float*)d_in[28], *ln3_b = (const float*)d_in[29];

    char* ws = (char*)d_ws;
    const size_t MB = 1024 * 1024;
    u16*   bw   = (u16*)(ws);
    u16*   xb   = (u16*)(ws + 8  * MB);
    u16*   encb = (u16*)(ws + 16 * MB);
    u16*   qkvB = (u16*)(ws + 24 * MB);
    u16*   qb   = (u16*)(ws + 24 * MB);
    u16*   ff1b = (u16*)(ws + 24 * MB);
    u16*   ob   = (u16*)(ws + 48 * MB);
    float* projF= (float*)(ws + 56 * MB);
    float* x1f  = (float*)(ws + 72 * MB);
    u16*   x1b  = (u16*)(ws + 88 * MB);
    u16*   x2b  = (u16*)(ws + 88 * MB);
    float* x2f  = (float*)(ws + 8  * MB);
    u16*   kvB  = (u16*)d_out;          // 16 MB scratch; dead until ln3 writes

    u16* wsaq = bw;
    u16* wsao = bw + 786432;
    u16* wcaq = bw + 1048576;
    u16* wcak = bw + 1310720;
    u16* wcao = bw + 1835008;
    u16* wff1 = bw + 2097152;
    u16* wff2 = bw + 3145728;

    // ---- prepass: ONE dispatch ----
    PreArgs pa;
    pa.x = x; pa.enc = enc; pa.xb = xb; pa.encb = encb;
    pa.wp.w[0]=sa_Wq; pa.wp.w[1]=sa_Wk; pa.wp.w[2]=sa_Wv; pa.wp.w[3]=sa_Wo;
    pa.wp.w[4]=ca_Wq; pa.wp.w[5]=ca_Wk; pa.wp.w[6]=ca_Wv; pa.wp.w[7]=ca_Wo;
    pa.bw = bw; pa.ffW1 = ff_W1; pa.wff1 = wff1; pa.ffW2 = ff_W2; pa.wff2 = wff2;
    prepass<<<dim3(12288), dim3(256), 0, stream>>>(pa);

    auto G128 = [&](const u16* A, const u16* Wt, const float* b0, const float* b1,
                    const float* b2, const float* b3, void* C,
                    int N, int K, int ldc, int out_bf, int relu) {
        dim3 grid(N / 128, Tt / 128);
        if (out_bf) {
            if (relu) gemm128<1,1><<<grid, dim3(256), 0, stream>>>(A, Wt, b0,b1,b2,b3, C, Tt, N, K, ldc);
            else      gemm128<1,0><<<grid, dim3(256), 0, stream>>>(A, Wt, b0,b1,b2,b3, C, Tt, N, K, ldc);
        } else        gemm128<0,0><<<grid, dim3(256), 0, stream>>>(A, Wt, b0,b1,b2,b3, C, Tt, N, K, ldc);
    };
    auto G64 = [&](const u16* A, const u16* Wt, const float* bi, void* C,
                   int K, int ldc, int out_bf) {
        dim3 grid(512 / 64, Tt / 128);
        if (out_bf) gemm64<1,0><<<grid, dim3(256), 0, stream>>>(A, Wt, bi, C, Tt, 512, K, ldc);
        else        gemm64<0,0><<<grid, dim3(256), 0, stream>>>(A, Wt, bi, C, Tt, 512, K, ldc);
    };
    const dim3 agrid(Sx / 128, Bx * Hx);    // (16, 32) = 512 blocks
    const dim3 lgrid(Tt / 4);               // ln_add: 4 rows/block

    // ---- stage 1: fused QKV+caKV GEMM, self-attn, proj, add&norm ----
    DualArgs da;
    da.A0 = xb;   da.B0 = wsaq; da.C0 = qkvB;
    da.qb0 = sa_bq; da.qb1 = sa_bk; da.qb2 = sa_bv;
    da.A1 = encb; da.B1 = wcak; da.C1 = kvB;
    da.cb0 = ca_bk; da.cb1 = ca_bv;
    gemm128_dual<<<dim3(20, Tt / 128), dim3(256), 0, stream>>>(da);

    attn_mfma<true><<<agrid, dim3(256), 0, stream>>>(qkvB, qkvB + 512, qkvB + 1024,
                                                     ob, 1536, 1536, 1536);
    G64(ob, wsao, sa_bo, projF, 512, 512, 0);
    ln_add<<<lgrid, dim3(256), 0, stream>>>(x, projF, ln1_g, ln1_b, x1f, x1b);

    // ---- stage 2: cross-attention + add&norm (kvB already computed) ----
    G64(x1b, wcaq, ca_bq, qb, 512, 512, 1);
    attn_mfma<false><<<agrid, dim3(256), 0, stream>>>(qb, kvB, kvB + 512,
                                                      ob, 512, 1024, 1024);
    G64(ob, wcao, ca_bo, projF, 512, 512, 0);
    ln_add<<<lgrid, dim3(256), 0, stream>>>(x1f, projF, ln2_g, ln2_b, x2f, x2b);

    // ---- stage 3: FFN + add&norm ----
    G128(x2b, wff1, ff_b1, ff_b1 + 512, ff_b1 + 1024, ff_b1 + 1536,
         ff1b, 2048, 512, 2048, 1, 1);                       // ReLU
    G64(ff1b, wff2, ff_b2, projF, 2048, 512, 0);
    ln_add<<<lgrid, dim3(256), 0, stream>>>(x2f, projF, ln3_g, ln3_b,
                                            (float*)d_out, (u16*)nullptr);
}

// Round 12
// 471.856 us; speedup vs baseline: 1.2203x; 1.2203x over previous
//
#include <hip/hip_runtime.h>

// Problem constants (B,S,E,H,DK,DV,DF) = (4,2048,512,8,64,64,2048)
#define Bx  4
#define Sx  2048
#define Ex  512
#define Hx  8
#define Tt  (Bx * Sx)          // 8192 tokens

typedef short          short8 __attribute__((ext_vector_type(8)));  // 8 bf16
typedef float          f32x4  __attribute__((ext_vector_type(4)));  // MFMA C/D
typedef unsigned short u16;

__device__ __forceinline__ u16 f2bf(float f) {
    unsigned int u = __float_as_uint(f);
    u += 0x7fffu + ((u >> 16) & 1u);          // round-to-nearest-even
    return (u16)(u >> 16);
}
__device__ __forceinline__ float bf2f(u16 h) {
    return __uint_as_float(((unsigned int)h) << 16);
}
// packed f32x2 -> bf16x2, RNE (bit-identical to f2bf); S0 -> [15:0], S1 -> [31:16]
__device__ __forceinline__ unsigned int cvt_pk_bf16(float lo, float hi) {
    unsigned int r;
    asm("v_cvt_pk_bf16_f32 %0, %1, %2" : "=v"(r) : "v"(lo), "v"(hi));
    return r;
}
// async global->LDS, 16B per lane. LDS dest is WAVE-UNIFORM base + lane*16
// (m104/m108); global source is per-lane. size must be a literal.
typedef const __attribute__((address_space(1))) void* gas1_t;
typedef __attribute__((address_space(3))) void*       las3_t;
__device__ __forceinline__ void gload16(const u16* g, u16* l) {
    __builtin_amdgcn_global_load_lds((gas1_t)g, (las3_t)l, 16, 0, 0);
}

struct WPtrs { const float* w[8]; };

// ---------------------------------------------------------------------------
// prepass: ALL pre-work in ONE dispatch. flat block id ranges:
//   [0,4096) x->bf16 | [4096,8192) enc->bf16 | [8192,10240) 8x 512^2 W^T
//   [10240,11264) ff_W1^T | [11264,12288) ff_W2^T
// ---------------------------------------------------------------------------
struct PreArgs {
    const float* x; const float* enc; u16* xb; u16* encb;
    WPtrs wp; u16* bw;
    const float* ffW1; u16* wff1;
    const float* ffW2; u16* wff2;
};
__global__ __launch_bounds__(256) void prepass(PreArgs a)
{
    __shared__ u16 tile[32][33];
    const int bid = blockIdx.x;
    const int tid = threadIdx.x;

    if (bid < 8192) {
        const float* in  = bid < 4096 ? a.x : a.enc;
        u16*         out = bid < 4096 ? a.xb : a.encb;
        const int bb = bid < 4096 ? bid : bid - 4096;
        const int i  = (bb * 256 + tid) << 2;
        float4 v = *(const float4*)(in + i);
        ushort4 o;
        o.x = f2bf(v.x); o.y = f2bf(v.y); o.z = f2bf(v.z); o.w = f2bf(v.w);
        *(ushort4*)(out + i) = o;
        return;
    }
    const float* W; u16* Wt; int K, N, bx, by;
    if (bid < 10240) {
        const int wi = bid - 8192, slot = wi >> 8, r = wi & 255;
        W = a.wp.w[slot]; Wt = a.bw + (size_t)slot * 262144;
        K = 512; N = 512; bx = r & 15; by = r >> 4;
    } else if (bid < 11264) {
        const int wi = bid - 10240;
        W = a.ffW1; Wt = a.wff1; K = 512; N = 2048; bx = wi & 63; by = wi >> 6;
    } else {
        const int wi = bid - 11264;
        W = a.ffW2; Wt = a.wff2; K = 2048; N = 512; bx = wi & 15; by = wi >> 4;
    }
    const int n0 = bx * 32, k0 = by * 32;
    const int tx = tid & 31, ty = tid >> 5;
#pragma unroll
    for (int i = 0; i < 32; i += 8)
        tile[ty + i][tx] = f2bf(W[(size_t)(k0 + ty + i) * N + n0 + tx]);
    __syncthreads();
#pragma unroll
    for (int i = 0; i < 32; i += 8)
        Wt[(size_t)(n0 + ty + i) * K + k0 + tx] = tile[tx][ty + i];
}

// ---------------------------------------------------------------------------
// gemm128 v2: 128x128 tile, BK=32, 256 thr = 4 waves (2x2), wave 64x64.
//   Staging via global_load_lds width=16 (m97 recipe). As/Bs LINEAR [128][32]
//   u16 (16KB, no pad). Wave w owns rows [w*32, w*32+32); LDS base is
//   wave-uniform, HW adds lane*16 -> row-major linear.
// ---------------------------------------------------------------------------
template<int OUT_BF16, int RELU>
__global__ __launch_bounds__(256) void gemm128(const u16* __restrict__ A,
                                               const u16* __restrict__ Bt,
                                               const float* __restrict__ b0,
                                               const float* __restrict__ b1,
                                               const float* __restrict__ b2,
                                               const float* __restrict__ b3,
                                               void* __restrict__ Cout,
                                               int M, int N, int K, int ldc)
{
    __shared__ u16 As[128 * 32];
    __shared__ u16 Bs[128 * 32];

    const int tid  = threadIdx.x;
    const int w    = tid >> 6;
    const int lane = tid & 63;
    const int c    = lane & 15;
    const int quad = lane >> 4;
    const int wr   = w >> 1, wc = w & 1;
    const int m0   = blockIdx.y * 128;
    const int n0   = blockIdx.x * 128;

    const int srow = lane >> 2;
    const int scol = (lane & 3) << 3;
    const u16* Ag0 = A  + (size_t)(m0 + w * 32 + srow) * K + scol;
    const u16* Ag1 = Ag0 + (size_t)16 * K;
    const u16* Bg0 = Bt + (size_t)(n0 + w * 32 + srow) * K + scol;
    const u16* Bg1 = Bg0 + (size_t)16 * K;
    u16* AsB0 = &As[(w * 2 + 0) * 512];
    u16* AsB1 = &As[(w * 2 + 1) * 512];
    u16* BsB0 = &Bs[(w * 2 + 0) * 512];
    u16* BsB1 = &Bs[(w * 2 + 1) * 512];

    f32x4 acc[4][4];
#pragma unroll
    for (int i = 0; i < 4; i++)
#pragma unroll
        for (int j = 0; j < 4; j++) { acc[i][j][0]=0.f; acc[i][j][1]=0.f; acc[i][j][2]=0.f; acc[i][j][3]=0.f; }

    for (int k0 = 0; k0 < K; k0 += 32) {
        __syncthreads();
        gload16(Ag0 + k0, AsB0);
        gload16(Ag1 + k0, AsB1);
        gload16(Bg0 + k0, BsB0);
        gload16(Bg1 + k0, BsB1);
        __syncthreads();

        short8 af[4], bf[4];
#pragma unroll
        for (int i = 0; i < 4; i++)
            af[i] = *(const short8*)&As[(wr * 64 + i * 16 + c) * 32 + quad * 8];
#pragma unroll
        for (int j = 0; j < 4; j++)
            bf[j] = *(const short8*)&Bs[(wc * 64 + j * 16 + c) * 32 + quad * 8];
#pragma unroll
        for (int i = 0; i < 4; i++)
#pragma unroll
            for (int j = 0; j < 4; j++)
                acc[i][j] = __builtin_amdgcn_mfma_f32_16x16x32_bf16(af[i], bf[j], acc[i][j], 0, 0, 0);
    }

    const int seg = n0 >> 9;
    const float* bp = seg == 0 ? b0 : (seg == 1 ? b1 : (seg == 2 ? b2 : b3));
    const int nbase = n0 & 511;
    float bv[4];
#pragma unroll
    for (int j = 0; j < 4; j++) bv[j] = bp[nbase + wc * 64 + j * 16 + c];

#pragma unroll
    for (int i = 0; i < 4; i++) {
#pragma unroll
        for (int j = 0; j < 4; j++) {
            int colg = n0 + wc * 64 + j * 16 + c;
#pragma unroll
            for (int r = 0; r < 4; r++) {
                int rowg = m0 + wr * 64 + i * 16 + quad * 4 + r;
                float v = acc[i][j][r] + bv[j];
                if (RELU) v = fmaxf(v, 0.f);
                if (OUT_BF16) ((u16*)Cout)[(size_t)rowg * ldc + colg] = f2bf(v);
                else          ((float*)Cout)[(size_t)rowg * ldc + colg] = v;
            }
        }
    }
}

// ---------------------------------------------------------------------------
// gemm128_dual: QKV (12 N-blocks) + caKV (8 N-blocks) in ONE launch.
// ---------------------------------------------------------------------------
struct DualArgs {
    const u16* A0; const u16* B0; u16* C0;          // QKV
    const float* qb0; const float* qb1; const float* qb2;
    const u16* A1; const u16* B1; u16* C1;          // caKV
    const float* cb0; const float* cb1;
};
__global__ __launch_bounds__(256) void gemm128_dual(DualArgs d)
{
    __shared__ u16 As[128 * 32];
    __shared__ u16 Bs[128 * 32];

    const int tid  = threadIdx.x;
    const int w    = tid >> 6;
    const int lane = tid & 63;
    const int c    = lane & 15;
    const int quad = lane >> 4;
    const int wr   = w >> 1, wc = w & 1;
    const int m0   = blockIdx.y * 128;

    const u16* A; const u16* Bt; u16* C; int ldc, n0; const float* bp;
    if ((int)blockIdx.x < 12) {
        A = d.A0; Bt = d.B0; C = d.C0; ldc = 1536; n0 = blockIdx.x * 128;
        const int seg = n0 >> 9;
        bp = seg == 0 ? d.qb0 : (seg == 1 ? d.qb1 : d.qb2);
    } else {
        A = d.A1; Bt = d.B1; C = d.C1; ldc = 1024; n0 = (blockIdx.x - 12) * 128;
        bp = (n0 >> 9) ? d.cb1 : d.cb0;
    }
    const int K = 512;

    const int srow = lane >> 2;
    const int scol = (lane & 3) << 3;
    const u16* Ag0 = A  + (size_t)(m0 + w * 32 + srow) * K + scol;
    const u16* Ag1 = Ag0 + (size_t)16 * K;
    const u16* Bg0 = Bt + (size_t)(n0 + w * 32 + srow) * K + scol;
    const u16* Bg1 = Bg0 + (size_t)16 * K;
    u16* AsB0 = &As[(w * 2 + 0) * 512];
    u16* AsB1 = &As[(w * 2 + 1) * 512];
    u16* BsB0 = &Bs[(w * 2 + 0) * 512];
    u16* BsB1 = &Bs[(w * 2 + 1) * 512];

    f32x4 acc[4][4];
#pragma unroll
    for (int i = 0; i < 4; i++)
#pragma unroll
        for (int j = 0; j < 4; j++) { acc[i][j][0]=0.f; acc[i][j][1]=0.f; acc[i][j][2]=0.f; acc[i][j][3]=0.f; }

    for (int k0 = 0; k0 < K; k0 += 32) {
        __syncthreads();
        gload16(Ag0 + k0, AsB0);
        gload16(Ag1 + k0, AsB1);
        gload16(Bg0 + k0, BsB0);
        gload16(Bg1 + k0, BsB1);
        __syncthreads();

        short8 af[4], bf[4];
#pragma unroll
        for (int i = 0; i < 4; i++)
            af[i] = *(const short8*)&As[(wr * 64 + i * 16 + c) * 32 + quad * 8];
#pragma unroll
        for (int j = 0; j < 4; j++)
            bf[j] = *(const short8*)&Bs[(wc * 64 + j * 16 + c) * 32 + quad * 8];
#pragma unroll
        for (int i = 0; i < 4; i++)
#pragma unroll
            for (int j = 0; j < 4; j++)
                acc[i][j] = __builtin_amdgcn_mfma_f32_16x16x32_bf16(af[i], bf[j], acc[i][j], 0, 0, 0);
    }

    const int nbase = n0 & 511;
    float bv[4];
#pragma unroll
    for (int j = 0; j < 4; j++) bv[j] = bp[nbase + wc * 64 + j * 16 + c];

#pragma unroll
    for (int i = 0; i < 4; i++) {
#pragma unroll
        for (int j = 0; j < 4; j++) {
            int colg = n0 + wc * 64 + j * 16 + c;
#pragma unroll
            for (int r = 0; r < 4; r++) {
                int rowg = m0 + wr * 64 + i * 16 + quad * 4 + r;
                C[(size_t)rowg * ldc + colg] = f2bf(acc[i][j][r] + bv[j]);
            }
        }
    }
}

// ---------------------------------------------------------------------------
// gemm64 v2: 128x64 tile, BK=32, 256 thr = 4 waves, direct-to-LDS staging.
// ---------------------------------------------------------------------------
template<int OUT_BF16, int RELU>
__global__ __launch_bounds__(256) void gemm64(const u16* __restrict__ A,
                                              const u16* __restrict__ Bt,
                                              const float* __restrict__ bias,
                                              void* __restrict__ Cout,
                                              int M, int N, int K, int ldc)
{
    __shared__ u16 As[128 * 32];
    __shared__ u16 Bs[64 * 32];

    const int tid  = threadIdx.x;
    const int w    = tid >> 6;          // 0..3
    const int lane = tid & 63;
    const int c    = lane & 15;
    const int quad = lane >> 4;
    const int m0   = blockIdx.y * 128;
    const int n0   = blockIdx.x * 64;

    const int srow = lane >> 2;
    const int scol = (lane & 3) << 3;
    const u16* Ag0 = A  + (size_t)(m0 + w * 32 + srow) * K + scol;
    const u16* Ag1 = Ag0 + (size_t)16 * K;
    const u16* Bg  = Bt + (size_t)(n0 + w * 16 + srow) * K + scol;
    u16* AsB0 = &As[(w * 2 + 0) * 512];
    u16* AsB1 = &As[(w * 2 + 1) * 512];
    u16* BsB  = &Bs[w * 512];

    f32x4 acc[2][4];
#pragma unroll
    for (int i = 0; i < 2; i++)
#pragma unroll
        for (int j = 0; j < 4; j++) { acc[i][j][0]=0.f; acc[i][j][1]=0.f; acc[i][j][2]=0.f; acc[i][j][3]=0.f; }

    for (int k0 = 0; k0 < K; k0 += 32) {
        __syncthreads();
        gload16(Ag0 + k0, AsB0);
        gload16(Ag1 + k0, AsB1);
        gload16(Bg  + k0, BsB);
        __syncthreads();

        short8 af[2], bf[4];
#pragma unroll
        for (int i = 0; i < 2; i++)
            af[i] = *(const short8*)&As[(w * 32 + i * 16 + c) * 32 + quad * 8];
#pragma unroll
        for (int j = 0; j < 4; j++)
            bf[j] = *(const short8*)&Bs[(j * 16 + c) * 32 + quad * 8];
#pragma unroll
        for (int i = 0; i < 2; i++)
#pragma unroll
            for (int j = 0; j < 4; j++)
                acc[i][j] = __builtin_amdgcn_mfma_f32_16x16x32_bf16(af[i], bf[j], acc[i][j], 0, 0, 0);
    }

    float bv[4];
#pragma unroll
    for (int j = 0; j < 4; j++) bv[j] = bias[n0 + j * 16 + c];

#pragma unroll
    for (int i = 0; i < 2; i++) {
#pragma unroll
        for (int j = 0; j < 4; j++) {
            int colg = n0 + j * 16 + c;
#pragma unroll
            for (int r = 0; r < 4; r++) {
                int rowg = m0 + w * 32 + i * 16 + quad * 4 + r;
                float v = acc[i][j][r] + bv[j];
                if (RELU) v = fmaxf(v, 0.f);
                if (OUT_BF16) ((u16*)Cout)[(size_t)rowg * ldc + colg] = f2bf(v);
                else          ((float*)Cout)[(size_t)rowg * ldc + colg] = v;
            }
        }
    }
}

// ---------------------------------------------------------------------------
// MFMA flash attention (v8/v10 config — measured best: 78.4us cross).
//   v11 post-mortem: per-wave register K loads quadrupled K VMEM ops
//   (each wave privately loading what LDS shared across 4 waves) and VGPR
//   140 halved occupancy -> 126us. REVERTED to block-shared K/V LDS
//   staging: 256-thr/4-wave blocks, grid (16,32)=512=2/CU; swapped QK^T
//   (P in registers), 32 q/wave (2 q-frags sharing all K/V LDS reads),
//   KVBLK=64 double-buffered (one barrier/tile), register prefetch,
//   cvt_pk P-pack, XCD swizzle (bijective), 72-u16 strides (144B rows;
//   bank-optimal: 8 dw/bank for wave64 b128 — no swizzle win available).
// No max-subtraction (|s|<~2): unnormalized O += P*V, l += sum(exp) ==
// reference softmax; p=0 == exp(-1e9) underflow.
// Layouts (m89/m91): A[m=lane&15][k=quad*8+j], B[k=quad*8+j][n=lane&15],
// C/D: col=lane&15, row=quad*4+reg. sigma(slot): qs=slot>>3, j=slot&7,
// key = (j<4 ? qs*4+j : 16+qs*4+j-4) (+32 second half); applied to both
// P-pack (A) and V^T staging (B) so it cancels.
// ---------------------------------------------------------------------------
template<bool CAUSAL>
__global__ __launch_bounds__(256) void attn_mfma(const u16* __restrict__ Q,
                                                 const u16* __restrict__ K,
                                                 const u16* __restrict__ V,
                                                 u16* __restrict__ O,
                                                 int ldq, int ldk, int ldv)
{
    __shared__ u16 Klds[2][64 * 72];       // [buf][key][dim], 144B rows
    __shared__ u16 Vtlds[2][64 * 72];      // [buf][dim][sigma-slot 0..63]

    const int tid  = threadIdx.x;
    const int w    = tid >> 6;
    const int lane = tid & 63;
    const int c    = lane & 15;
    const int quad = lane >> 4;

    const int flat = blockIdx.y * 16 + blockIdx.x;
    const int idx  = flat >> 3;
    const int bh   = (flat & 7) * 4 + (idx >> 4);
    const int q0   = (idx & 15) * 128;

    const int b    = bh >> 3;
    const int h    = bh & 7;
    const int bS   = b * Sx;
    const int hoff = h * 64;
    const int qw   = q0 + w * 32;

    const int kkey = tid >> 3;
    const int kc8  = (tid & 7) << 3;
    const int vdim = tid & 63;
    const int vq   = tid >> 6;
    const int vp   = vq << 3;
    int vkey[8];
#pragma unroll
    for (int j = 0; j < 8; j++) vkey[j] = ((j & 4) << 2) + (vq << 2) + (j & 3);

    short8 qa[2][2];
#pragma unroll
    for (int a = 0; a < 2; a++) {
        const u16* qp = Q + (size_t)(bS + qw + a * 16 + c) * ldq + hoff;
        qa[a][0] = *(const short8*)(qp + quad * 8);
        qa[a][1] = *(const short8*)(qp + 32 + quad * 8);
    }

    f32x4 of[2][4];
#pragma unroll
    for (int a = 0; a < 2; a++)
#pragma unroll
        for (int f = 0; f < 4; f++) { of[a][f][0]=0.f; of[a][f][1]=0.f; of[a][f][2]=0.f; of[a][f][3]=0.f; }
    float lpart[2] = {0.f, 0.f};

    const int kend = CAUSAL ? (q0 + 128) : Sx;

    const u16* Kgp = K + (size_t)(bS + kkey) * ldk + hoff + kc8;
    const u16* Vgp = V + (size_t)bS * ldv + hoff + vdim;
    const size_t k32 = (size_t)32 * ldk;

    {
        short8 kr0 = *(const short8*)(Kgp);
        short8 kr1 = *(const short8*)(Kgp + k32);
        union { short8 v; u16 u[8]; } vb0, vb1;
#pragma unroll
        for (int j = 0; j < 8; j++) vb0.u[j] = Vgp[(size_t)vkey[j] * ldv];
#pragma unroll
        for (int j = 0; j < 8; j++) vb1.u[j] = Vgp[(size_t)(32 + vkey[j]) * ldv];
        *(short8*)&Klds[0][kkey * 72 + kc8]        = kr0;
        *(short8*)&Klds[0][(kkey + 32) * 72 + kc8] = kr1;
        *(short8*)&Vtlds[0][vdim * 72 + vp]        = vb0.v;
        *(short8*)&Vtlds[0][vdim * 72 + 32 + vp]   = vb1.v;
    }
    __syncthreads();

    int cur = 0;
    for (int kt = 0; kt < kend; kt += 64) {
        const bool more = (kt + 64 < kend);

        short8 kr0, kr1;
        union { short8 v; u16 u[8]; } vb0, vb1;
        if (more) {
            const u16* kp = Kgp + (size_t)(kt + 64) * ldk;
            kr0 = *(const short8*)(kp);
            kr1 = *(const short8*)(kp + k32);
#pragma unroll
            for (int j = 0; j < 8; j++)
                vb0.u[j] = Vgp[(size_t)(kt + 64 + vkey[j]) * ldv];
#pragma unroll
            for (int j = 0; j < 8; j++)
                vb1.u[j] = Vgp[(size_t)(kt + 96 + vkey[j]) * ldv];
        }

        int fm0 = 4, fm1 = 4;
        if (CAUSAL) {
            int d0 = ((qw + 15 - kt) >> 4) + 1;
            int d1 = ((qw + 31 - kt) >> 4) + 1;
            fm0 = d0 < 0 ? 0 : (d0 > 4 ? 4 : d0);
            fm1 = d1 < 0 ? 0 : (d1 > 4 ? 4 : d1);
        }

        if (fm1 > 0) {
            f32x4 s[2][4];
#pragma unroll
            for (int f = 0; f < 4; f++) {
                if (f < fm1) {
                    short8 kb0 = *(const short8*)&Klds[cur][(f * 16 + c) * 72 + quad * 8];
                    short8 kb1 = *(const short8*)&Klds[cur][(f * 16 + c) * 72 + 32 + quad * 8];
#pragma unroll
                    for (int a = 0; a < 2; a++) {
                        const int fma_ = a ? fm1 : fm0;
                        if (f < fma_) {
                            f32x4 z; z[0]=0.f; z[1]=0.f; z[2]=0.f; z[3]=0.f;
                            z = __builtin_amdgcn_mfma_f32_16x16x32_bf16(kb0, qa[a][0], z, 0, 0, 0);
                            z = __builtin_amdgcn_mfma_f32_16x16x32_bf16(kb1, qa[a][1], z, 0, 0, 0);
                            s[a][f] = z;
                        }
                    }
                }
            }

            union { unsigned int u[4]; short8 s8; } paA[2], paB[2];
#pragma unroll
            for (int a = 0; a < 2; a++) {
                const int fma_ = a ? fm1 : fm0;
                const int qg = qw + a * 16 + c;
#pragma unroll
                for (int f = 0; f < 4; f++) {
                    float p[4];
#pragma unroll
                    for (int r = 0; r < 4; r++) {
                        float pv = 0.f;
                        int kg = kt + f * 16 + quad * 4 + r;
                        if (f < fma_ && !(CAUSAL && kg > qg))
                            pv = __expf(s[a][f][r] * 0.125f);
                        p[r] = pv;
                    }
                    unsigned int w0 = cvt_pk_bf16(p[0], p[1]);
                    unsigned int w1 = cvt_pk_bf16(p[2], p[3]);
                    lpart[a] += __uint_as_float(w0 << 16) + __uint_as_float(w0 & 0xffff0000u);
                    lpart[a] += __uint_as_float(w1 << 16) + __uint_as_float(w1 & 0xffff0000u);
                    if (f < 2) { paA[a].u[f * 2] = w0; paA[a].u[f * 2 + 1] = w1; }
                    else       { paB[a].u[(f - 2) * 2] = w0; paB[a].u[(f - 2) * 2 + 1] = w1; }
                }
            }

#pragma unroll
            for (int f2 = 0; f2 < 4; f2++) {
                short8 vb0f = *(const short8*)&Vtlds[cur][(f2 * 16 + c) * 72 + quad * 8];
                short8 vb1f = *(const short8*)&Vtlds[cur][(f2 * 16 + c) * 72 + 32 + quad * 8];
                if (fm0 > 0)
                    of[0][f2] = __builtin_amdgcn_mfma_f32_16x16x32_bf16(paA[0].s8, vb0f, of[0][f2], 0, 0, 0);
                of[1][f2] = __builtin_amdgcn_mfma_f32_16x16x32_bf16(paA[1].s8, vb0f, of[1][f2], 0, 0, 0);
                if (fm0 > 2)
                    of[0][f2] = __builtin_amdgcn_mfma_f32_16x16x32_bf16(paB[0].s8, vb1f, of[0][f2], 0, 0, 0);
                if (fm1 > 2)
                    of[1][f2] = __builtin_amdgcn_mfma_f32_16x16x32_bf16(paB[1].s8, vb1f, of[1][f2], 0, 0, 0);
            }
        }

        if (more) {
            *(short8*)&Klds[cur ^ 1][kkey * 72 + kc8]        = kr0;
            *(short8*)&Klds[cur ^ 1][(kkey + 32) * 72 + kc8] = kr1;
            *(short8*)&Vtlds[cur ^ 1][vdim * 72 + vp]        = vb0.v;
            *(short8*)&Vtlds[cur ^ 1][vdim * 72 + 32 + vp]   = vb1.v;
        }
        __syncthreads();
        cur ^= 1;
    }

    float rinv[2][4];
#pragma unroll
    for (int a = 0; a < 2; a++) {
        float D = lpart[a];
        D += __shfl_xor(D, 16, 64);
        D += __shfl_xor(D, 32, 64);
        float rcp = 1.f / D;
#pragma unroll
        for (int r = 0; r < 4; r++)
            rinv[a][r] = __shfl(rcp, quad * 4 + r, 64);
    }

    u16* Ob = O + (size_t)(bS + qw) * Ex + hoff;
#pragma unroll
    for (int a = 0; a < 2; a++)
#pragma unroll
        for (int f = 0; f < 4; f++)
#pragma unroll
            for (int r = 0; r < 4; r++)
                Ob[(size_t)(a * 16 + quad * 4 + r) * Ex + f * 16 + c] =
                    f2bf(of[a][f][r] * rinv[a][r]);
}

// ---------------------------------------------------------------------------
// Fused residual-add + LayerNorm: one wave per row, 4 rows/block.
// ---------------------------------------------------------------------------
__global__ __launch_bounds__(256) void ln_add(const float* __restrict__ x,
                                              const float* __restrict__ s,
                                              const float* __restrict__ g,
                                              const float* __restrict__ bta,
                                              float* __restrict__ out,
                                              u16* __restrict__ out_bf)
{
    const int t    = threadIdx.x;
    const int w    = t >> 6;
    const int lane = t & 63;
    const int row  = blockIdx.x * 4 + w;
    const size_t base = (size_t)row * Ex + lane * 8;
    const int    gi   = lane * 8;

    float4 xv0 = *(const float4*)(x + base);
    float4 xv1 = *(const float4*)(x + base + 4);
    float4 sv0 = *(const float4*)(s + base);
    float4 sv1 = *(const float4*)(s + base + 4);
    float y[8] = { xv0.x + sv0.x, xv0.y + sv0.y, xv0.z + sv0.z, xv0.w + sv0.w,
                   xv1.x + sv1.x, xv1.y + sv1.y, xv1.z + sv1.z, xv1.w + sv1.w };

    float sum = 0.f, sq = 0.f;
#pragma unroll
    for (int i = 0; i < 8; i++) { sum += y[i]; sq += y[i] * y[i]; }
#pragma unroll
    for (int o = 1; o < 64; o <<= 1) {
        sum += __shfl_xor(sum, o, 64);
        sq  += __shfl_xor(sq,  o, 64);
    }

    const float mean = sum * (1.f / 512.f);
    const float var  = sq * (1.f / 512.f) - mean * mean;
    const float rstd = rsqrtf(var + 1e-3f);

    float4 gv0 = *(const float4*)(g + gi);
    float4 gv1 = *(const float4*)(g + gi + 4);
    float4 bv0 = *(const float4*)(bta + gi);
    float4 bv1 = *(const float4*)(bta + gi + 4);
    float gg[8] = { gv0.x, gv0.y, gv0.z, gv0.w, gv1.x, gv1.y, gv1.z, gv1.w };
    float bb[8] = { bv0.x, bv0.y, bv0.z, bv0.w, bv1.x, bv1.y, bv1.z, bv1.w };

    float o8[8];
#pragma unroll
    for (int i = 0; i < 8; i++) o8[i] = (y[i] - mean) * rstd * gg[i] + bb[i];

    *(float4*)(out + base)     = make_float4(o8[0], o8[1], o8[2], o8[3]);
    *(float4*)(out + base + 4) = make_float4(o8[4], o8[5], o8[6], o8[7]);
    if (out_bf) {
        union { short8 v; u16 u[8]; } ob;
#pragma unroll
        for (int i = 0; i < 8; i++) ob.u[i] = f2bf(o8[i]);
        *(short8*)(out_bf + base) = ob.v;
    }
}

// ---------------------------------------------------------------------------
// Orchestration (12 dispatches). 96 MB workspace (MB offsets):
//   [0,8) bw | [8,16) xb / P3 x2f=[8,24) | [16,24) encb
//   [24,48) qkvB | P2 qb=[24,32) | P3 ff1b=[24,56) | [48,56) ob
//   [56,72) projF | [72,88) x1f | [88,96) x1b/x2b
//   kvB -> d_out scratch (dead until ln3 writes it last).
// ---------------------------------------------------------------------------
extern "C" void kernel_launch(void* const* d_in, const int* in_sizes, int n_in,
                              void* d_out, int out_size, void* d_ws, size_t ws_size,
                              hipStream_t stream)
{
    const float* x     = (const float*)d_in[0];
    const float* enc   = (const float*)d_in[1];
    const float* sa_Wq = (const float*)d_in[4],  *sa_bq = (const float*)d_in[5];
    const float* sa_Wk = (const float*)d_in[6],  *sa_bk = (const float*)d_in[7];
    const float* sa_Wv = (const float*)d_in[8],  *sa_bv = (const float*)d_in[9];
    const float* sa_Wo = (const float*)d_in[10], *sa_bo = (const float*)d_in[11];
    const float* ca_Wq = (const float*)d_in[12], *ca_bq = (const float*)d_in[13];
    const float* ca_Wk = (const float*)d_in[14], *ca_bk = (const float*)d_in[15];
    const float* ca_Wv = (const float*)d_in[16], *ca_bv = (const float*)d_in[17];
    const float* ca_Wo = (const float*)d_in[18], *ca_bo = (const float*)d_in[19];
    const float* ff_W1 = (const float*)d_in[20], *ff_b1 = (const float*)d_in[21];
    const float* ff_W2 = (const float*)d_in[22], *ff_b2 = (const float*)d_in[23];
    const float* ln1_g = (const float*)d_in[24], *ln1_b = (const float*)d_in[25];
    const float* ln2_g = (const float*)d_in[26], *ln2_b = (const float*)d_in[27];
    const float* ln3_g = (const float*)d_in[28], *ln3_b = (const float*)d_in[29];

    char* ws = (char*)d_ws;
    const size_t MB = 1024 * 1024;
    u16*   bw   = (u16*)(ws);
    u16*   xb   = (u16*)(ws + 8  * MB);
    u16*   encb = (u16*)(ws + 16 * MB);
    u16*   qkvB = (u16*)(ws + 24 * MB);
    u16*   qb   = (u16*)(ws + 24 * MB);
    u16*   ff1b = (u16*)(ws + 24 * MB);
    u16*   ob   = (u16*)(ws + 48 * MB);
    float* projF= (float*)(ws + 56 * MB);
    float* x1f  = (float*)(ws + 72 * MB);
    u16*   x1b  = (u16*)(ws + 88 * MB);
    u16*   x2b  = (u16*)(ws + 88 * MB);
    float* x2f  = (float*)(ws + 8  * MB);
    u16*   kvB  = (u16*)d_out;          // 16 MB scratch; dead until ln3 writes

    u16* wsaq = bw;
    u16* wsao = bw + 786432;
    u16* wcaq = bw + 1048576;
    u16* wcak = bw + 1310720;
    u16* wcao = bw + 1835008;
    u16* wff1 = bw + 2097152;
    u16* wff2 = bw + 3145728;

    // ---- prepass: ONE dispatch ----
    PreArgs pa;
    pa.x = x; pa.enc = enc; pa.xb = xb; pa.encb = encb;
    pa.wp.w[0]=sa_Wq; pa.wp.w[1]=sa_Wk; pa.wp.w[2]=sa_Wv; pa.wp.w[3]=sa_Wo;
    pa.wp.w[4]=ca_Wq; pa.wp.w[5]=ca_Wk; pa.wp.w[6]=ca_Wv; pa.wp.w[7]=ca_Wo;
    pa.bw = bw; pa.ffW1 = ff_W1; pa.wff1 = wff1; pa.ffW2 = ff_W2; pa.wff2 = wff2;
    prepass<<<dim3(12288), dim3(256), 0, stream>>>(pa);

    auto G128 = [&](const u16* A, const u16* Wt, const float* b0, const float* b1,
                    const float* b2, const float* b3, void* C,
                    int N, int K, int ldc, int out_bf, int relu) {
        dim3 grid(N / 128, Tt / 128);
        if (out_bf) {
            if (relu) gemm128<1,1><<<grid, dim3(256), 0, stream>>>(A, Wt, b0,b1,b2,b3, C, Tt, N, K, ldc);
            else      gemm128<1,0><<<grid, dim3(256), 0, stream>>>(A, Wt, b0,b1,b2,b3, C, Tt, N, K, ldc);
        } else        gemm128<0,0><<<grid, dim3(256), 0, stream>>>(A, Wt, b0,b1,b2,b3, C, Tt, N, K, ldc);
    };
    auto G64 = [&](const u16* A, const u16* Wt, const float* bi, void* C,
                   int K, int ldc, int out_bf) {
        dim3 grid(512 / 64, Tt / 128);
        if (out_bf) gemm64<1,0><<<grid, dim3(256), 0, stream>>>(A, Wt, bi, C, Tt, 512, K, ldc);
        else        gemm64<0,0><<<grid, dim3(256), 0, stream>>>(A, Wt, bi, C, Tt, 512, K, ldc);
    };
    const dim3 agrid(Sx / 128, Bx * Hx);    // (16, 32) = 512 blocks
    const dim3 lgrid(Tt / 4);               // ln_add: 4 rows/block

    // ---- stage 1: fused QKV+caKV GEMM, self-attn, proj, add&norm ----
    DualArgs da;
    da.A0 = xb;   da.B0 = wsaq; da.C0 = qkvB;
    da.qb0 = sa_bq; da.qb1 = sa_bk; da.qb2 = sa_bv;
    da.A1 = encb; da.B1 = wcak; da.C1 = kvB;
    da.cb0 = ca_bk; da.cb1 = ca_bv;
    gemm128_dual<<<dim3(20, Tt / 128), dim3(256), 0, stream>>>(da);

    attn_mfma<true><<<agrid, dim3(256), 0, stream>>>(qkvB, qkvB + 512, qkvB + 1024,
                                                     ob, 1536, 1536, 1536);
    G64(ob, wsao, sa_bo, projF, 512, 512, 0);
    ln_add<<<lgrid, dim3(256), 0, stream>>>(x, projF, ln1_g, ln1_b, x1f, x1b);

    // ---- stage 2: cross-attention + add&norm (kvB already computed) ----
    G64(x1b, wcaq, ca_bq, qb, 512, 512, 1);
    attn_mfma<false><<<agrid, dim3(256), 0, stream>>>(qb, kvB, kvB + 512,
                                                      ob, 512, 1024, 1024);
    G64(ob, wcao, ca_bo, projF, 512, 512, 0);
    ln_add<<<lgrid, dim3(256), 0, stream>>>(x1f, projF, ln2_g, ln2_b, x2f, x2b);

    // ---- stage 3: FFN + add&norm ----
    G128(x2b, wff1, ff_b1, ff_b1 + 512, ff_b1 + 1024, ff_b1 + 1536,
         ff1b, 2048, 512, 2048, 1, 1);                       // ReLU
    G64(ff1b, wff2, ff_b2, projF, 2048, 512, 0);
    ln_add<<<lgrid, dim3(256), 0, stream>>>(x2f, projF, ln3_g, ln3_b,
                                            (float*)d_out, (u16*)nullptr);
}

// Round 14
// 449.883 us; speedup vs baseline: 1.2799x; 1.0488x over previous
//
#include <hip/hip_runtime.h>

// Problem constants (B,S,E,H,DK,DV,DF) = (4,2048,512,8,64,64,2048)
#define Bx  4
#define Sx  2048
#define Ex  512
#define Hx  8
#define Tt  (Bx * Sx)          // 8192 tokens

typedef short          short8 __attribute__((ext_vector_type(8)));  // 8 bf16
typedef float          f32x4  __attribute__((ext_vector_type(4)));  // MFMA C/D
typedef unsigned short u16;

__device__ __forceinline__ u16 f2bf(float f) {
    unsigned int u = __float_as_uint(f);
    u += 0x7fffu + ((u >> 16) & 1u);          // round-to-nearest-even
    return (u16)(u >> 16);
}
__device__ __forceinline__ float bf2f(u16 h) {
    return __uint_as_float(((unsigned int)h) << 16);
}
// packed f32x2 -> bf16x2, RNE (bit-identical to f2bf); S0 -> [15:0], S1 -> [31:16]
__device__ __forceinline__ unsigned int cvt_pk_bf16(float lo, float hi) {
    unsigned int r;
    asm("v_cvt_pk_bf16_f32 %0, %1, %2" : "=v"(r) : "v"(lo), "v"(hi));
    return r;
}
// async global->LDS, 16B per lane. LDS dest is WAVE-UNIFORM base + lane*16
// (m104/m108); global source is per-lane. size must be a literal.
typedef const __attribute__((address_space(1))) void* gas1_t;
typedef __attribute__((address_space(3))) void*       las3_t;
__device__ __forceinline__ void gload16(const u16* g, u16* l) {
    __builtin_amdgcn_global_load_lds((gas1_t)g, (las3_t)l, 16, 0, 0);
}

struct WPtrs { const float* w[8]; };

// ---------------------------------------------------------------------------
// prepass: ALL pre-work in ONE dispatch. flat block id ranges:
//   [0,4096) x->bf16 | [4096,8192) enc->bf16 | [8192,10240) 8x 512^2 W^T
//   [10240,11264) ff_W1^T | [11264,12288) ff_W2^T      (unchanged)
// ---------------------------------------------------------------------------
struct PreArgs {
    const float* x; const float* enc; u16* xb; u16* encb;
    WPtrs wp; u16* bw;
    const float* ffW1; u16* wff1;
    const float* ffW2; u16* wff2;
};
__global__ __launch_bounds__(256) void prepass(PreArgs a)
{
    __shared__ u16 tile[32][33];
    const int bid = blockIdx.x;
    const int tid = threadIdx.x;

    if (bid < 8192) {
        const float* in  = bid < 4096 ? a.x : a.enc;
        u16*         out = bid < 4096 ? a.xb : a.encb;
        const int bb = bid < 4096 ? bid : bid - 4096;
        const int i  = (bb * 256 + tid) << 2;
        float4 v = *(const float4*)(in + i);
        ushort4 o;
        o.x = f2bf(v.x); o.y = f2bf(v.y); o.z = f2bf(v.z); o.w = f2bf(v.w);
        *(ushort4*)(out + i) = o;
        return;
    }
    const float* W; u16* Wt; int K, N, bx, by;
    if (bid < 10240) {
        const int wi = bid - 8192, slot = wi >> 8, r = wi & 255;
        W = a.wp.w[slot]; Wt = a.bw + (size_t)slot * 262144;
        K = 512; N = 512; bx = r & 15; by = r >> 4;
    } else if (bid < 11264) {
        const int wi = bid - 10240;
        W = a.ffW1; Wt = a.wff1; K = 512; N = 2048; bx = wi & 63; by = wi >> 6;
    } else {
        const int wi = bid - 11264;
        W = a.ffW2; Wt = a.wff2; K = 2048; N = 512; bx = wi & 15; by = wi >> 4;
    }
    const int n0 = bx * 32, k0 = by * 32;
    const int tx = tid & 31, ty = tid >> 5;
#pragma unroll
    for (int i = 0; i < 32; i += 8)
        tile[ty + i][tx] = f2bf(W[(size_t)(k0 + ty + i) * N + n0 + tx]);
    __syncthreads();
#pragma unroll
    for (int i = 0; i < 32; i += 8)
        Wt[(size_t)(n0 + ty + i) * K + k0 + tx] = tile[tx][ty + i];
}

// ---------------------------------------------------------------------------
// XCD-aware flat-id swizzle (T1). All GEMM grids have nwg % 8 == 0, so the
// chunked remap is bijective: XCD k gets flat range [k*nwg/8, (k+1)*nwg/8).
// ---------------------------------------------------------------------------
__device__ __forceinline__ int xcd_flat()
{
    const int nx = gridDim.x;
    const int nwg = nx * gridDim.y;
    int flat = blockIdx.y * nx + blockIdx.x;
    return (flat & 7) * (nwg >> 3) + (flat >> 3);
}

// ---------------------------------------------------------------------------
// gemm128 v3: 128x128 tile, BK=32, 256 thr = 4 waves (2x2), wave 64x64.
//   v13: single-barrier LDS DOUBLE-BUFFER + XCD swizzle. Issue next-tile
//   gloads BEFORE compute; one barrier per step drains them after a full
//   compute phase of flight time (in-session precedent: attn v3->v5).
//   Barrier hazard audit: barrier's vmcnt(0)+lgkmcnt(0) drain gives RAW for
//   buf[cur^1] next iter; prior iter's barrier orders all reads of buf[cur^1]
//   before this iter's loads are issued (WAR). All barriers block-uniform.
// ---------------------------------------------------------------------------
template<int OUT_BF16, int RELU>
__global__ __launch_bounds__(256) void gemm128(const u16* __restrict__ A,
                                               const u16* __restrict__ Bt,
                                               const float* __restrict__ b0,
                                               const float* __restrict__ b1,
                                               const float* __restrict__ b2,
                                               const float* __restrict__ b3,
                                               void* __restrict__ Cout,
                                               int M, int N, int K, int ldc)
{
    __shared__ u16 As[2][128 * 32];
    __shared__ u16 Bs[2][128 * 32];

    const int tid  = threadIdx.x;
    const int w    = tid >> 6;
    const int lane = tid & 63;
    const int c    = lane & 15;
    const int quad = lane >> 4;
    const int wr   = w >> 1, wc = w & 1;

    const int flat = xcd_flat();
    const int m0   = (flat / gridDim.x) * 128;
    const int n0   = (flat % gridDim.x) * 128;

    const int srow = lane >> 2;
    const int scol = (lane & 3) << 3;
    const u16* Ag0 = A  + (size_t)(m0 + w * 32 + srow) * K + scol;
    const u16* Ag1 = Ag0 + (size_t)16 * K;
    const u16* Bg0 = Bt + (size_t)(n0 + w * 32 + srow) * K + scol;
    const u16* Bg1 = Bg0 + (size_t)16 * K;
    const int ao0 = (w * 2 + 0) * 512;
    const int ao1 = (w * 2 + 1) * 512;

    f32x4 acc[4][4];
#pragma unroll
    for (int i = 0; i < 4; i++)
#pragma unroll
        for (int j = 0; j < 4; j++) { acc[i][j][0]=0.f; acc[i][j][1]=0.f; acc[i][j][2]=0.f; acc[i][j][3]=0.f; }

    // prologue: stage tile 0 into buf 0 (one exposed drain per block)
    gload16(Ag0, &As[0][ao0]);
    gload16(Ag1, &As[0][ao1]);
    gload16(Bg0, &Bs[0][ao0]);
    gload16(Bg1, &Bs[0][ao1]);
    __syncthreads();

    int cur = 0;
    for (int k0 = 0; k0 < K; k0 += 32) {
        if (k0 + 32 < K) {                       // issue next tile FIRST
            gload16(Ag0 + k0 + 32, &As[cur ^ 1][ao0]);
            gload16(Ag1 + k0 + 32, &As[cur ^ 1][ao1]);
            gload16(Bg0 + k0 + 32, &Bs[cur ^ 1][ao0]);
            gload16(Bg1 + k0 + 32, &Bs[cur ^ 1][ao1]);
        }
        short8 af[4], bf[4];
#pragma unroll
        for (int i = 0; i < 4; i++)
            af[i] = *(const short8*)&As[cur][(wr * 64 + i * 16 + c) * 32 + quad * 8];
#pragma unroll
        for (int j = 0; j < 4; j++)
            bf[j] = *(const short8*)&Bs[cur][(wc * 64 + j * 16 + c) * 32 + quad * 8];
#pragma unroll
        for (int i = 0; i < 4; i++)
#pragma unroll
            for (int j = 0; j < 4; j++)
                acc[i][j] = __builtin_amdgcn_mfma_f32_16x16x32_bf16(af[i], bf[j], acc[i][j], 0, 0, 0);
        __syncthreads();                         // drains next-tile loads + WAR
        cur ^= 1;
    }

    const int seg = n0 >> 9;
    const float* bp = seg == 0 ? b0 : (seg == 1 ? b1 : (seg == 2 ? b2 : b3));
    const int nbase = n0 & 511;
    float bv[4];
#pragma unroll
    for (int j = 0; j < 4; j++) bv[j] = bp[nbase + wc * 64 + j * 16 + c];

#pragma unroll
    for (int i = 0; i < 4; i++) {
#pragma unroll
        for (int j = 0; j < 4; j++) {
            int colg = n0 + wc * 64 + j * 16 + c;
#pragma unroll
            for (int r = 0; r < 4; r++) {
                int rowg = m0 + wr * 64 + i * 16 + quad * 4 + r;
                float v = acc[i][j][r] + bv[j];
                if (RELU) v = fmaxf(v, 0.f);
                if (OUT_BF16) ((u16*)Cout)[(size_t)rowg * ldc + colg] = f2bf(v);
                else          ((float*)Cout)[(size_t)rowg * ldc + colg] = v;
            }
        }
    }
}

// ---------------------------------------------------------------------------
// gemm128_dual v2: QKV (12 N-blocks) + caKV (8 N-blocks) in ONE launch,
//   with v13 single-barrier dbuf + XCD swizzle. grid (20,64) = 1280 = 8*160.
// ---------------------------------------------------------------------------
struct DualArgs {
    const u16* A0; const u16* B0; u16* C0;          // QKV
    const float* qb0; const float* qb1; const float* qb2;
    const u16* A1; const u16* B1; u16* C1;          // caKV
    const float* cb0; const float* cb1;
};
__global__ __launch_bounds__(256) void gemm128_dual(DualArgs d)
{
    __shared__ u16 As[2][128 * 32];
    __shared__ u16 Bs[2][128 * 32];

    const int tid  = threadIdx.x;
    const int w    = tid >> 6;
    const int lane = tid & 63;
    const int c    = lane & 15;
    const int quad = lane >> 4;
    const int wr   = w >> 1, wc = w & 1;

    const int flat = xcd_flat();
    const int bxs  = flat % 20;
    const int m0   = (flat / 20) * 128;

    const u16* A; const u16* Bt; u16* C; int ldc, n0; const float* bp;
    if (bxs < 12) {
        A = d.A0; Bt = d.B0; C = d.C0; ldc = 1536; n0 = bxs * 128;
        const int seg = n0 >> 9;
        bp = seg == 0 ? d.qb0 : (seg == 1 ? d.qb1 : d.qb2);
    } else {
        A = d.A1; Bt = d.B1; C = d.C1; ldc = 1024; n0 = (bxs - 12) * 128;
        bp = (n0 >> 9) ? d.cb1 : d.cb0;
    }
    const int K = 512;

    const int srow = lane >> 2;
    const int scol = (lane & 3) << 3;
    const u16* Ag0 = A  + (size_t)(m0 + w * 32 + srow) * K + scol;
    const u16* Ag1 = Ag0 + (size_t)16 * K;
    const u16* Bg0 = Bt + (size_t)(n0 + w * 32 + srow) * K + scol;
    const u16* Bg1 = Bg0 + (size_t)16 * K;
    const int ao0 = (w * 2 + 0) * 512;
    const int ao1 = (w * 2 + 1) * 512;

    f32x4 acc[4][4];
#pragma unroll
    for (int i = 0; i < 4; i++)
#pragma unroll
        for (int j = 0; j < 4; j++) { acc[i][j][0]=0.f; acc[i][j][1]=0.f; acc[i][j][2]=0.f; acc[i][j][3]=0.f; }

    gload16(Ag0, &As[0][ao0]);
    gload16(Ag1, &As[0][ao1]);
    gload16(Bg0, &Bs[0][ao0]);
    gload16(Bg1, &Bs[0][ao1]);
    __syncthreads();

    int cur = 0;
    for (int k0 = 0; k0 < K; k0 += 32) {
        if (k0 + 32 < K) {
            gload16(Ag0 + k0 + 32, &As[cur ^ 1][ao0]);
            gload16(Ag1 + k0 + 32, &As[cur ^ 1][ao1]);
            gload16(Bg0 + k0 + 32, &Bs[cur ^ 1][ao0]);
            gload16(Bg1 + k0 + 32, &Bs[cur ^ 1][ao1]);
        }
        short8 af[4], bf[4];
#pragma unroll
        for (int i = 0; i < 4; i++)
            af[i] = *(const short8*)&As[cur][(wr * 64 + i * 16 + c) * 32 + quad * 8];
#pragma unroll
        for (int j = 0; j < 4; j++)
            bf[j] = *(const short8*)&Bs[cur][(wc * 64 + j * 16 + c) * 32 + quad * 8];
#pragma unroll
        for (int i = 0; i < 4; i++)
#pragma unroll
            for (int j = 0; j < 4; j++)
                acc[i][j] = __builtin_amdgcn_mfma_f32_16x16x32_bf16(af[i], bf[j], acc[i][j], 0, 0, 0);
        __syncthreads();
        cur ^= 1;
    }

    const int nbase = n0 & 511;
    float bv[4];
#pragma unroll
    for (int j = 0; j < 4; j++) bv[j] = bp[nbase + wc * 64 + j * 16 + c];

#pragma unroll
    for (int i = 0; i < 4; i++) {
#pragma unroll
        for (int j = 0; j < 4; j++) {
            int colg = n0 + wc * 64 + j * 16 + c;
#pragma unroll
            for (int r = 0; r < 4; r++) {
                int rowg = m0 + wr * 64 + i * 16 + quad * 4 + r;
                C[(size_t)rowg * ldc + colg] = f2bf(acc[i][j][r] + bv[j]);
            }
        }
    }
}

// ---------------------------------------------------------------------------
// gemm64 v3: 128x64 tile, BK=32, 256 thr = 4 waves; v13 single-barrier dbuf
//   + XCD swizzle. grid (8,64) = 512 = 8*64.
// ---------------------------------------------------------------------------
template<int OUT_BF16, int RELU>
__global__ __launch_bounds__(256) void gemm64(const u16* __restrict__ A,
                                              const u16* __restrict__ Bt,
                                              const float* __restrict__ bias,
                                              void* __restrict__ Cout,
                                              int M, int N, int K, int ldc)
{
    __shared__ u16 As[2][128 * 32];
    __shared__ u16 Bs[2][64 * 32];

    const int tid  = threadIdx.x;
    const int w    = tid >> 6;          // 0..3
    const int lane = tid & 63;
    const int c    = lane & 15;
    const int quad = lane >> 4;

    const int flat = xcd_flat();
    const int m0   = (flat / gridDim.x) * 128;
    const int n0   = (flat % gridDim.x) * 64;

    const int srow = lane >> 2;
    const int scol = (lane & 3) << 3;
    const u16* Ag0 = A  + (size_t)(m0 + w * 32 + srow) * K + scol;
    const u16* Ag1 = Ag0 + (size_t)16 * K;
    const u16* Bg  = Bt + (size_t)(n0 + w * 16 + srow) * K + scol;
    const int ao0 = (w * 2 + 0) * 512;
    const int ao1 = (w * 2 + 1) * 512;
    const int bo  = w * 512;

    f32x4 acc[2][4];
#pragma unroll
    for (int i = 0; i < 2; i++)
#pragma unroll
        for (int j = 0; j < 4; j++) { acc[i][j][0]=0.f; acc[i][j][1]=0.f; acc[i][j][2]=0.f; acc[i][j][3]=0.f; }

    gload16(Ag0, &As[0][ao0]);
    gload16(Ag1, &As[0][ao1]);
    gload16(Bg,  &Bs[0][bo]);
    __syncthreads();

    int cur = 0;
    for (int k0 = 0; k0 < K; k0 += 32) {
        if (k0 + 32 < K) {
            gload16(Ag0 + k0 + 32, &As[cur ^ 1][ao0]);
            gload16(Ag1 + k0 + 32, &As[cur ^ 1][ao1]);
            gload16(Bg  + k0 + 32, &Bs[cur ^ 1][bo]);
        }
        short8 af[2], bf[4];
#pragma unroll
        for (int i = 0; i < 2; i++)
            af[i] = *(const short8*)&As[cur][(w * 32 + i * 16 + c) * 32 + quad * 8];
#pragma unroll
        for (int j = 0; j < 4; j++)
            bf[j] = *(const short8*)&Bs[cur][(j * 16 + c) * 32 + quad * 8];
#pragma unroll
        for (int i = 0; i < 2; i++)
#pragma unroll
            for (int j = 0; j < 4; j++)
                acc[i][j] = __builtin_amdgcn_mfma_f32_16x16x32_bf16(af[i], bf[j], acc[i][j], 0, 0, 0);
        __syncthreads();
        cur ^= 1;
    }

    float bv[4];
#pragma unroll
    for (int j = 0; j < 4; j++) bv[j] = bias[n0 + j * 16 + c];

#pragma unroll
    for (int i = 0; i < 2; i++) {
#pragma unroll
        for (int j = 0; j < 4; j++) {
            int colg = n0 + j * 16 + c;
#pragma unroll
            for (int r = 0; r < 4; r++) {
                int rowg = m0 + w * 32 + i * 16 + quad * 4 + r;
                float v = acc[i][j][r] + bv[j];
                if (RELU) v = fmaxf(v, 0.f);
                if (OUT_BF16) ((u16*)Cout)[(size_t)rowg * ldc + colg] = f2bf(v);
                else          ((float*)Cout)[(size_t)rowg * ldc + colg] = v;
            }
        }
    }
}

// ---------------------------------------------------------------------------
// MFMA flash attention (v8/v10 config — measured best: 78.4us cross).
//   UNCHANGED. 256-thr/4-wave blocks, grid (16,32)=512=2/CU; swapped QK^T
//   (P in registers), 32 q/wave, KVBLK=64 double-buffered (one barrier/tile),
//   register prefetch, cvt_pk P-pack, XCD swizzle, 72-u16 strides.
// No max-subtraction (|s|<~2): unnormalized O += P*V, l += sum(exp) ==
// reference softmax; p=0 == exp(-1e9) underflow.
// Layouts (m89/m91): A[m=lane&15][k=quad*8+j], B[k=quad*8+j][n=lane&15],
// C/D: col=lane&15, row=quad*4+reg. sigma(slot): qs=slot>>3, j=slot&7,
// key = (j<4 ? qs*4+j : 16+qs*4+j-4) (+32 second half); applied to both
// P-pack (A) and V^T staging (B) so it cancels.
// ---------------------------------------------------------------------------
template<bool CAUSAL>
__global__ __launch_bounds__(256) void attn_mfma(const u16* __restrict__ Q,
                                                 const u16* __restrict__ K,
                                                 const u16* __restrict__ V,
                                                 u16* __restrict__ O,
                                                 int ldq, int ldk, int ldv)
{
    __shared__ u16 Klds[2][64 * 72];       // [buf][key][dim], 144B rows
    __shared__ u16 Vtlds[2][64 * 72];      // [buf][dim][sigma-slot 0..63]

    const int tid  = threadIdx.x;
    const int w    = tid >> 6;
    const int lane = tid & 63;
    const int c    = lane & 15;
    const int quad = lane >> 4;

    const int flat = blockIdx.y * 16 + blockIdx.x;
    const int idx  = flat >> 3;
    const int bh   = (flat & 7) * 4 + (idx >> 4);
    const int q0   = (idx & 15) * 128;

    const int b    = bh >> 3;
    const int h    = bh & 7;
    const int bS   = b * Sx;
    const int hoff = h * 64;
    const int qw   = q0 + w * 32;

    const int kkey = tid >> 3;
    const int kc8  = (tid & 7) << 3;
    const int vdim = tid & 63;
    const int vq   = tid >> 6;
    const int vp   = vq << 3;
    int vkey[8];
#pragma unroll
    for (int j = 0; j < 8; j++) vkey[j] = ((j & 4) << 2) + (vq << 2) + (j & 3);

    short8 qa[2][2];
#pragma unroll
    for (int a = 0; a < 2; a++) {
        const u16* qp = Q + (size_t)(bS + qw + a * 16 + c) * ldq + hoff;
        qa[a][0] = *(const short8*)(qp + quad * 8);
        qa[a][1] = *(const short8*)(qp + 32 + quad * 8);
    }

    f32x4 of[2][4];
#pragma unroll
    for (int a = 0; a < 2; a++)
#pragma unroll
        for (int f = 0; f < 4; f++) { of[a][f][0]=0.f; of[a][f][1]=0.f; of[a][f][2]=0.f; of[a][f][3]=0.f; }
    float lpart[2] = {0.f, 0.f};

    const int kend = CAUSAL ? (q0 + 128) : Sx;

    const u16* Kgp = K + (size_t)(bS + kkey) * ldk + hoff + kc8;
    const u16* Vgp = V + (size_t)bS * ldv + hoff + vdim;
    const size_t k32 = (size_t)32 * ldk;

    {
        short8 kr0 = *(const short8*)(Kgp);
        short8 kr1 = *(const short8*)(Kgp + k32);
        union { short8 v; u16 u[8]; } vb0, vb1;
#pragma unroll
        for (int j = 0; j < 8; j++) vb0.u[j] = Vgp[(size_t)vkey[j] * ldv];
#pragma unroll
        for (int j = 0; j < 8; j++) vb1.u[j] = Vgp[(size_t)(32 + vkey[j]) * ldv];
        *(short8*)&Klds[0][kkey * 72 + kc8]        = kr0;
        *(short8*)&Klds[0][(kkey + 32) * 72 + kc8] = kr1;
        *(short8*)&Vtlds[0][vdim * 72 + vp]        = vb0.v;
        *(short8*)&Vtlds[0][vdim * 72 + 32 + vp]   = vb1.v;
    }
    __syncthreads();

    int cur = 0;
    for (int kt = 0; kt < kend; kt += 64) {
        const bool more = (kt + 64 < kend);

        short8 kr0, kr1;
        union { short8 v; u16 u[8]; } vb0, vb1;
        if (more) {
            const u16* kp = Kgp + (size_t)(kt + 64) * ldk;
            kr0 = *(const short8*)(kp);
            kr1 = *(const short8*)(kp + k32);
#pragma unroll
            for (int j = 0; j < 8; j++)
                vb0.u[j] = Vgp[(size_t)(kt + 64 + vkey[j]) * ldv];
#pragma unroll
            for (int j = 0; j < 8; j++)
                vb1.u[j] = Vgp[(size_t)(kt + 96 + vkey[j]) * ldv];
        }

        int fm0 = 4, fm1 = 4;
        if (CAUSAL) {
            int d0 = ((qw + 15 - kt) >> 4) + 1;
            int d1 = ((qw + 31 - kt) >> 4) + 1;
            fm0 = d0 < 0 ? 0 : (d0 > 4 ? 4 : d0);
            fm1 = d1 < 0 ? 0 : (d1 > 4 ? 4 : d1);
        }

        if (fm1 > 0) {
            f32x4 s[2][4];
#pragma unroll
            for (int f = 0; f < 4; f++) {
                if (f < fm1) {
                    short8 kb0 = *(const short8*)&Klds[cur][(f * 16 + c) * 72 + quad * 8];
                    short8 kb1 = *(const short8*)&Klds[cur][(f * 16 + c) * 72 + 32 + quad * 8];
#pragma unroll
                    for (int a = 0; a < 2; a++) {
                        const int fma_ = a ? fm1 : fm0;
                        if (f < fma_) {
                            f32x4 z; z[0]=0.f; z[1]=0.f; z[2]=0.f; z[3]=0.f;
                            z = __builtin_amdgcn_mfma_f32_16x16x32_bf16(kb0, qa[a][0], z, 0, 0, 0);
                            z = __builtin_amdgcn_mfma_f32_16x16x32_bf16(kb1, qa[a][1], z, 0, 0, 0);
                            s[a][f] = z;
                        }
                    }
                }
            }

            union { unsigned int u[4]; short8 s8; } paA[2], paB[2];
#pragma unroll
            for (int a = 0; a < 2; a++) {
                const int fma_ = a ? fm1 : fm0;
                const int qg = qw + a * 16 + c;
#pragma unroll
                for (int f = 0; f < 4; f++) {
                    float p[4];
#pragma unroll
                    for (int r = 0; r < 4; r++) {
                        float pv = 0.f;
                        int kg = kt + f * 16 + quad * 4 + r;
                        if (f < fma_ && !(CAUSAL && kg > qg))
                            pv = __expf(s[a][f][r] * 0.125f);
                        p[r] = pv;
                    }
                    unsigned int w0 = cvt_pk_bf16(p[0], p[1]);
                    unsigned int w1 = cvt_pk_bf16(p[2], p[3]);
                    lpart[a] += __uint_as_float(w0 << 16) + __uint_as_float(w0 & 0xffff0000u);
                    lpart[a] += __uint_as_float(w1 << 16) + __uint_as_float(w1 & 0xffff0000u);
                    if (f < 2) { paA[a].u[f * 2] = w0; paA[a].u[f * 2 + 1] = w1; }
                    else       { paB[a].u[(f - 2) * 2] = w0; paB[a].u[(f - 2) * 2 + 1] = w1; }
                }
            }

#pragma unroll
            for (int f2 = 0; f2 < 4; f2++) {
                short8 vb0f = *(const short8*)&Vtlds[cur][(f2 * 16 + c) * 72 + quad * 8];
                short8 vb1f = *(const short8*)&Vtlds[cur][(f2 * 16 + c) * 72 + 32 + quad * 8];
                if (fm0 > 0)
                    of[0][f2] = __builtin_amdgcn_mfma_f32_16x16x32_bf16(paA[0].s8, vb0f, of[0][f2], 0, 0, 0);
                of[1][f2] = __builtin_amdgcn_mfma_f32_16x16x32_bf16(paA[1].s8, vb0f, of[1][f2], 0, 0, 0);
                if (fm0 > 2)
                    of[0][f2] = __builtin_amdgcn_mfma_f32_16x16x32_bf16(paB[0].s8, vb1f, of[0][f2], 0, 0, 0);
                if (fm1 > 2)
                    of[1][f2] = __builtin_amdgcn_mfma_f32_16x16x32_bf16(paB[1].s8, vb1f, of[1][f2], 0, 0, 0);
            }
        }

        if (more) {
            *(short8*)&Klds[cur ^ 1][kkey * 72 + kc8]        = kr0;
            *(short8*)&Klds[cur ^ 1][(kkey + 32) * 72 + kc8] = kr1;
            *(short8*)&Vtlds[cur ^ 1][vdim * 72 + vp]        = vb0.v;
            *(short8*)&Vtlds[cur ^ 1][vdim * 72 + 32 + vp]   = vb1.v;
        }
        __syncthreads();
        cur ^= 1;
    }

    float rinv[2][4];
#pragma unroll
    for (int a = 0; a < 2; a++) {
        float D = lpart[a];
        D += __shfl_xor(D, 16, 64);
        D += __shfl_xor(D, 32, 64);
        float rcp = 1.f / D;
#pragma unroll
        for (int r = 0; r < 4; r++)
            rinv[a][r] = __shfl(rcp, quad * 4 + r, 64);
    }

    u16* Ob = O + (size_t)(bS + qw) * Ex + hoff;
#pragma unroll
    for (int a = 0; a < 2; a++)
#pragma unroll
        for (int f = 0; f < 4; f++)
#pragma unroll
            for (int r = 0; r < 4; r++)
                Ob[(size_t)(a * 16 + quad * 4 + r) * Ex + f * 16 + c] =
                    f2bf(of[a][f][r] * rinv[a][r]);
}

// ---------------------------------------------------------------------------
// Fused residual-add + LayerNorm: one wave per row, 4 rows/block. (unchanged)
// ---------------------------------------------------------------------------
__global__ __launch_bounds__(256) void ln_add(const float* __restrict__ x,
                                              const float* __restrict__ s,
                                              const float* __restrict__ g,
                                              const float* __restrict__ bta,
                                              float* __restrict__ out,
                                              u16* __restrict__ out_bf)
{
    const int t    = threadIdx.x;
    const int w    = t >> 6;
    const int lane = t & 63;
    const int row  = blockIdx.x * 4 + w;
    const size_t base = (size_t)row * Ex + lane * 8;
    const int    gi   = lane * 8;

    float4 xv0 = *(const float4*)(x + base);
    float4 xv1 = *(const float4*)(x + base + 4);
    float4 sv0 = *(const float4*)(s + base);
    float4 sv1 = *(const float4*)(s + base + 4);
    float y[8] = { xv0.x + sv0.x, xv0.y + sv0.y, xv0.z + sv0.z, xv0.w + sv0.w,
                   xv1.x + sv1.x, xv1.y + sv1.y, xv1.z + sv1.z, xv1.w + sv1.w };

    float sum = 0.f, sq = 0.f;
#pragma unroll
    for (int i = 0; i < 8; i++) { sum += y[i]; sq += y[i] * y[i]; }
#pragma unroll
    for (int o = 1; o < 64; o <<= 1) {
        sum += __shfl_xor(sum, o, 64);
        sq  += __shfl_xor(sq,  o, 64);
    }

    const float mean = sum * (1.f / 512.f);
    const float var  = sq * (1.f / 512.f) - mean * mean;
    const float rstd = rsqrtf(var + 1e-3f);

    float4 gv0 = *(const float4*)(g + gi);
    float4 gv1 = *(const float4*)(g + gi + 4);
    float4 bv0 = *(const float4*)(bta + gi);
    float4 bv1 = *(const float4*)(bta + gi + 4);
    float gg[8] = { gv0.x, gv0.y, gv0.z, gv0.w, gv1.x, gv1.y, gv1.z, gv1.w };
    float bb[8] = { bv0.x, bv0.y, bv0.z, bv0.w, bv1.x, bv1.y, bv1.z, bv1.w };

    float o8[8];
#pragma unroll
    for (int i = 0; i < 8; i++) o8[i] = (y[i] - mean) * rstd * gg[i] + bb[i];

    *(float4*)(out + base)     = make_float4(o8[0], o8[1], o8[2], o8[3]);
    *(float4*)(out + base + 4) = make_float4(o8[4], o8[5], o8[6], o8[7]);
    if (out_bf) {
        union { short8 v; u16 u[8]; } ob;
#pragma unroll
        for (int i = 0; i < 8; i++) ob.u[i] = f2bf(o8[i]);
        *(short8*)(out_bf + base) = ob.v;
    }
}

// ---------------------------------------------------------------------------
// Orchestration (12 dispatches). 96 MB workspace (MB offsets):
//   [0,8) bw | [8,16) xb / P3 x2f=[8,24) | [16,24) encb
//   [24,48) qkvB | P2 qb=[24,32) | P3 ff1b=[24,56) | [48,56) ob
//   [56,72) projF | [72,88) x1f | [88,96) x1b/x2b
//   kvB -> d_out scratch (dead until ln3 writes it last).
// ---------------------------------------------------------------------------
extern "C" void kernel_launch(void* const* d_in, const int* in_sizes, int n_in,
                              void* d_out, int out_size, void* d_ws, size_t ws_size,
                              hipStream_t stream)
{
    const float* x     = (const float*)d_in[0];
    const float* enc   = (const float*)d_in[1];
    const float* sa_Wq = (const float*)d_in[4],  *sa_bq = (const float*)d_in[5];
    const float* sa_Wk = (const float*)d_in[6],  *sa_bk = (const float*)d_in[7];
    const float* sa_Wv = (const float*)d_in[8],  *sa_bv = (const float*)d_in[9];
    const float* sa_Wo = (const float*)d_in[10], *sa_bo = (const float*)d_in[11];
    const float* ca_Wq = (const float*)d_in[12], *ca_bq = (const float*)d_in[13];
    const float* ca_Wk = (const float*)d_in[14], *ca_bk = (const float*)d_in[15];
    const float* ca_Wv = (const float*)d_in[16], *ca_bv = (const float*)d_in[17];
    const float* ca_Wo = (const float*)d_in[18], *ca_bo = (const float*)d_in[19];
    const float* ff_W1 = (const float*)d_in[20], *ff_b1 = (const float*)d_in[21];
    const float* ff_W2 = (const float*)d_in[22], *ff_b2 = (const float*)d_in[23];
    const float* ln1_g = (const float*)d_in[24], *ln1_b = (const float*)d_in[25];
    const float* ln2_g = (const float*)d_in[26], *ln2_b = (const float*)d_in[27];
    const float* ln3_g = (const float*)d_in[28], *ln3_b = (const float*)d_in[29];

    char* ws = (char*)d_ws;
    const size_t MB = 1024 * 1024;
    u16*   bw   = (u16*)(ws);
    u16*   xb   = (u16*)(ws + 8  * MB);
    u16*   encb = (u16*)(ws + 16 * MB);
    u16*   qkvB = (u16*)(ws + 24 * MB);
    u16*   qb   = (u16*)(ws + 24 * MB);
    u16*   ff1b = (u16*)(ws + 24 * MB);
    u16*   ob   = (u16*)(ws + 48 * MB);
    float* projF= (float*)(ws + 56 * MB);
    float* x1f  = (float*)(ws + 72 * MB);
    u16*   x1b  = (u16*)(ws + 88 * MB);
    u16*   x2b  = (u16*)(ws + 88 * MB);
    float* x2f  = (float*)(ws + 8  * MB);
    u16*   kvB  = (u16*)d_out;          // 16 MB scratch; dead until ln3 writes

    u16* wsaq = bw;
    u16* wsao = bw + 786432;
    u16* wcaq = bw + 1048576;
    u16* wcak = bw + 1310720;
    u16* wcao = bw + 1835008;
    u16* wff1 = bw + 2097152;
    u16* wff2 = bw + 3145728;

    // ---- prepass: ONE dispatch ----
    PreArgs pa;
    pa.x = x; pa.enc = enc; pa.xb = xb; pa.encb = encb;
    pa.wp.w[0]=sa_Wq; pa.wp.w[1]=sa_Wk; pa.wp.w[2]=sa_Wv; pa.wp.w[3]=sa_Wo;
    pa.wp.w[4]=ca_Wq; pa.wp.w[5]=ca_Wk; pa.wp.w[6]=ca_Wv; pa.wp.w[7]=ca_Wo;
    pa.bw = bw; pa.ffW1 = ff_W1; pa.wff1 = wff1; pa.ffW2 = ff_W2; pa.wff2 = wff2;
    prepass<<<dim3(12288), dim3(256), 0, stream>>>(pa);

    auto G128 = [&](const u16* A, const u16* Wt, const float* b0, const float* b1,
                    const float* b2, const float* b3, void* C,
                    int N, int K, int ldc, int out_bf, int relu) {
        dim3 grid(N / 128, Tt / 128);
        if (out_bf) {
            if (relu) gemm128<1,1><<<grid, dim3(256), 0, stream>>>(A, Wt, b0,b1,b2,b3, C, Tt, N, K, ldc);
            else      gemm128<1,0><<<grid, dim3(256), 0, stream>>>(A, Wt, b0,b1,b2,b3, C, Tt, N, K, ldc);
        } else        gemm128<0,0><<<grid, dim3(256), 0, stream>>>(A, Wt, b0,b1,b2,b3, C, Tt, N, K, ldc);
    };
    auto G64 = [&](const u16* A, const u16* Wt, const float* bi, void* C,
                   int K, int ldc, int out_bf) {
        dim3 grid(512 / 64, Tt / 128);
        if (out_bf) gemm64<1,0><<<grid, dim3(256), 0, stream>>>(A, Wt, bi, C, Tt, 512, K, ldc);
        else        gemm64<0,0><<<grid, dim3(256), 0, stream>>>(A, Wt, bi, C, Tt, 512, K, ldc);
    };
    const dim3 agrid(Sx / 128, Bx * Hx);    // (16, 32) = 512 blocks
    const dim3 lgrid(Tt / 4);               // ln_add: 4 rows/block

    // ---- stage 1: fused QKV+caKV GEMM, self-attn, proj, add&norm ----
    DualArgs da;
    da.A0 = xb;   da.B0 = wsaq; da.C0 = qkvB;
    da.qb0 = sa_bq; da.qb1 = sa_bk; da.qb2 = sa_bv;
    da.A1 = encb; da.B1 = wcak; da.C1 = kvB;
    da.cb0 = ca_bk; da.cb1 = ca_bv;
    gemm128_dual<<<dim3(20, Tt / 128), dim3(256), 0, stream>>>(da);

    attn_mfma<true><<<agrid, dim3(256), 0, stream>>>(qkvB, qkvB + 512, qkvB + 1024,
                                                     ob, 1536, 1536, 1536);
    G64(ob, wsao, sa_bo, projF, 512, 512, 0);
    ln_add<<<lgrid, dim3(256), 0, stream>>>(x, projF, ln1_g, ln1_b, x1f, x1b);

    // ---- stage 2: cross-attention + add&norm (kvB already computed) ----
    G64(x1b, wcaq, ca_bq, qb, 512, 512, 1);
    attn_mfma<false><<<agrid, dim3(256), 0, stream>>>(qb, kvB, kvB + 512,
                                                      ob, 512, 1024, 1024);
    G64(ob, wcao, ca_bo, projF, 512, 512, 0);
    ln_add<<<lgrid, dim3(256), 0, stream>>>(x1f, projF, ln2_g, ln2_b, x2f, x2b);

    // ---- stage 3: FFN + add&norm ----
    G128(x2b, wff1, ff_b1, ff_b1 + 512, ff_b1 + 1024, ff_b1 + 1536,
         ff1b, 2048, 512, 2048, 1, 1);                       // ReLU
    G64(ff1b, wff2, ff_b2, projF, 2048, 512, 0);
    ln_add<<<lgrid, dim3(256), 0, stream>>>(x2f, projF, ln3_g, ln3_b,
                                            (float*)d_out, (u16*)nullptr);
}

// Round 15
// 438.896 us; speedup vs baseline: 1.3119x; 1.0250x over previous
//
#include <hip/hip_runtime.h>

// Problem constants (B,S,E,H,DK,DV,DF) = (4,2048,512,8,64,64,2048)
#define Bx  4
#define Sx  2048
#define Ex  512
#define Hx  8
#define Tt  (Bx * Sx)          // 8192 tokens

typedef short          short8 __attribute__((ext_vector_type(8)));  // 8 bf16
typedef float          f32x4  __attribute__((ext_vector_type(4)));  // MFMA C/D
typedef unsigned short u16;

__device__ __forceinline__ u16 f2bf(float f) {
    unsigned int u = __float_as_uint(f);
    u += 0x7fffu + ((u >> 16) & 1u);          // round-to-nearest-even
    return (u16)(u >> 16);
}
__device__ __forceinline__ float bf2f(u16 h) {
    return __uint_as_float(((unsigned int)h) << 16);
}
// packed f32x2 -> bf16x2, RNE (bit-identical to f2bf); S0 -> [15:0], S1 -> [31:16]
__device__ __forceinline__ unsigned int cvt_pk_bf16(float lo, float hi) {
    unsigned int r;
    asm("v_cvt_pk_bf16_f32 %0, %1, %2" : "=v"(r) : "v"(lo), "v"(hi));
    return r;
}
// async global->LDS, 16B per lane. LDS dest is WAVE-UNIFORM base + lane*16
// (m104/m108); global source is per-lane. size must be a literal.
typedef const __attribute__((address_space(1))) void* gas1_t;
typedef __attribute__((address_space(3))) void*       las3_t;
__device__ __forceinline__ void gload16(const u16* g, u16* l) {
    __builtin_amdgcn_global_load_lds((gas1_t)g, (las3_t)l, 16, 0, 0);
}

struct WPtrs { const float* w[8]; };

// ---------------------------------------------------------------------------
// prepass: ALL pre-work in ONE dispatch. flat block id ranges:
//   [0,4096) x->bf16 | [4096,8192) enc->bf16 | [8192,10240) 8x 512^2 W^T
//   [10240,11264) ff_W1^T | [11264,12288) ff_W2^T      (unchanged)
// ---------------------------------------------------------------------------
struct PreArgs {
    const float* x; const float* enc; u16* xb; u16* encb;
    WPtrs wp; u16* bw;
    const float* ffW1; u16* wff1;
    const float* ffW2; u16* wff2;
};
__global__ __launch_bounds__(256) void prepass(PreArgs a)
{
    __shared__ u16 tile[32][33];
    const int bid = blockIdx.x;
    const int tid = threadIdx.x;

    if (bid < 8192) {
        const float* in  = bid < 4096 ? a.x : a.enc;
        u16*         out = bid < 4096 ? a.xb : a.encb;
        const int bb = bid < 4096 ? bid : bid - 4096;
        const int i  = (bb * 256 + tid) << 2;
        float4 v = *(const float4*)(in + i);
        ushort4 o;
        o.x = f2bf(v.x); o.y = f2bf(v.y); o.z = f2bf(v.z); o.w = f2bf(v.w);
        *(ushort4*)(out + i) = o;
        return;
    }
    const float* W; u16* Wt; int K, N, bx, by;
    if (bid < 10240) {
        const int wi = bid - 8192, slot = wi >> 8, r = wi & 255;
        W = a.wp.w[slot]; Wt = a.bw + (size_t)slot * 262144;
        K = 512; N = 512; bx = r & 15; by = r >> 4;
    } else if (bid < 11264) {
        const int wi = bid - 10240;
        W = a.ffW1; Wt = a.wff1; K = 512; N = 2048; bx = wi & 63; by = wi >> 6;
    } else {
        const int wi = bid - 11264;
        W = a.ffW2; Wt = a.wff2; K = 2048; N = 512; bx = wi & 15; by = wi >> 4;
    }
    const int n0 = bx * 32, k0 = by * 32;
    const int tx = tid & 31, ty = tid >> 5;
#pragma unroll
    for (int i = 0; i < 32; i += 8)
        tile[ty + i][tx] = f2bf(W[(size_t)(k0 + ty + i) * N + n0 + tx]);
    __syncthreads();
#pragma unroll
    for (int i = 0; i < 32; i += 8)
        Wt[(size_t)(n0 + ty + i) * K + k0 + tx] = tile[tx][ty + i];
}

// ---------------------------------------------------------------------------
// XCD-aware flat-id swizzle (T1). All GEMM grids have nwg % 8 == 0, so the
// chunked remap is bijective: XCD k gets flat range [k*nwg/8, (k+1)*nwg/8).
// ---------------------------------------------------------------------------
__device__ __forceinline__ int xcd_flat()
{
    const int nx = gridDim.x;
    const int nwg = nx * gridDim.y;
    int flat = blockIdx.y * nx + blockIdx.x;
    return (flat & 7) * (nwg >> 3) + (flat >> 3);
}

// ---------------------------------------------------------------------------
// gemm128 v3: 128x128 tile, BK=32, 256 thr = 4 waves (2x2), wave 64x64.
//   Single-barrier LDS double-buffer + XCD swizzle (measured: -22us total
//   across GEMM chain, round 14). Issue next-tile gloads BEFORE compute;
//   one barrier per step drains them after a full compute phase.
// ---------------------------------------------------------------------------
template<int OUT_BF16, int RELU>
__global__ __launch_bounds__(256) void gemm128(const u16* __restrict__ A,
                                               const u16* __restrict__ Bt,
                                               const float* __restrict__ b0,
                                               const float* __restrict__ b1,
                                               const float* __restrict__ b2,
                                               const float* __restrict__ b3,
                                               void* __restrict__ Cout,
                                               int M, int N, int K, int ldc)
{
    __shared__ u16 As[2][128 * 32];
    __shared__ u16 Bs[2][128 * 32];

    const int tid  = threadIdx.x;
    const int w    = tid >> 6;
    const int lane = tid & 63;
    const int c    = lane & 15;
    const int quad = lane >> 4;
    const int wr   = w >> 1, wc = w & 1;

    const int flat = xcd_flat();
    const int m0   = (flat / gridDim.x) * 128;
    const int n0   = (flat % gridDim.x) * 128;

    const int srow = lane >> 2;
    const int scol = (lane & 3) << 3;
    const u16* Ag0 = A  + (size_t)(m0 + w * 32 + srow) * K + scol;
    const u16* Ag1 = Ag0 + (size_t)16 * K;
    const u16* Bg0 = Bt + (size_t)(n0 + w * 32 + srow) * K + scol;
    const u16* Bg1 = Bg0 + (size_t)16 * K;
    const int ao0 = (w * 2 + 0) * 512;
    const int ao1 = (w * 2 + 1) * 512;

    f32x4 acc[4][4];
#pragma unroll
    for (int i = 0; i < 4; i++)
#pragma unroll
        for (int j = 0; j < 4; j++) { acc[i][j][0]=0.f; acc[i][j][1]=0.f; acc[i][j][2]=0.f; acc[i][j][3]=0.f; }

    // prologue: stage tile 0 into buf 0 (one exposed drain per block)
    gload16(Ag0, &As[0][ao0]);
    gload16(Ag1, &As[0][ao1]);
    gload16(Bg0, &Bs[0][ao0]);
    gload16(Bg1, &Bs[0][ao1]);
    __syncthreads();

    int cur = 0;
    for (int k0 = 0; k0 < K; k0 += 32) {
        if (k0 + 32 < K) {                       // issue next tile FIRST
            gload16(Ag0 + k0 + 32, &As[cur ^ 1][ao0]);
            gload16(Ag1 + k0 + 32, &As[cur ^ 1][ao1]);
            gload16(Bg0 + k0 + 32, &Bs[cur ^ 1][ao0]);
            gload16(Bg1 + k0 + 32, &Bs[cur ^ 1][ao1]);
        }
        short8 af[4], bf[4];
#pragma unroll
        for (int i = 0; i < 4; i++)
            af[i] = *(const short8*)&As[cur][(wr * 64 + i * 16 + c) * 32 + quad * 8];
#pragma unroll
        for (int j = 0; j < 4; j++)
            bf[j] = *(const short8*)&Bs[cur][(wc * 64 + j * 16 + c) * 32 + quad * 8];
#pragma unroll
        for (int i = 0; i < 4; i++)
#pragma unroll
            for (int j = 0; j < 4; j++)
                acc[i][j] = __builtin_amdgcn_mfma_f32_16x16x32_bf16(af[i], bf[j], acc[i][j], 0, 0, 0);
        __syncthreads();                         // drains next-tile loads + WAR
        cur ^= 1;
    }

    const int seg = n0 >> 9;
    const float* bp = seg == 0 ? b0 : (seg == 1 ? b1 : (seg == 2 ? b2 : b3));
    const int nbase = n0 & 511;
    float bv[4];
#pragma unroll
    for (int j = 0; j < 4; j++) bv[j] = bp[nbase + wc * 64 + j * 16 + c];

#pragma unroll
    for (int i = 0; i < 4; i++) {
#pragma unroll
        for (int j = 0; j < 4; j++) {
            int colg = n0 + wc * 64 + j * 16 + c;
#pragma unroll
            for (int r = 0; r < 4; r++) {
                int rowg = m0 + wr * 64 + i * 16 + quad * 4 + r;
                float v = acc[i][j][r] + bv[j];
                if (RELU) v = fmaxf(v, 0.f);
                if (OUT_BF16) ((u16*)Cout)[(size_t)rowg * ldc + colg] = f2bf(v);
                else          ((float*)Cout)[(size_t)rowg * ldc + colg] = v;
            }
        }
    }
}

// ---------------------------------------------------------------------------
// gemm128_dual v2: QKV (12 N-blocks) + caKV (8 N-blocks) in ONE launch,
//   single-barrier dbuf + XCD swizzle. grid (20,64) = 1280 = 8*160.
// ---------------------------------------------------------------------------
struct DualArgs {
    const u16* A0; const u16* B0; u16* C0;          // QKV
    const float* qb0; const float* qb1; const float* qb2;
    const u16* A1; const u16* B1; u16* C1;          // caKV
    const float* cb0; const float* cb1;
};
__global__ __launch_bounds__(256) void gemm128_dual(DualArgs d)
{
    __shared__ u16 As[2][128 * 32];
    __shared__ u16 Bs[2][128 * 32];

    const int tid  = threadIdx.x;
    const int w    = tid >> 6;
    const int lane = tid & 63;
    const int c    = lane & 15;
    const int quad = lane >> 4;
    const int wr   = w >> 1, wc = w & 1;

    const int flat = xcd_flat();
    const int bxs  = flat % 20;
    const int m0   = (flat / 20) * 128;

    const u16* A; const u16* Bt; u16* C; int ldc, n0; const float* bp;
    if (bxs < 12) {
        A = d.A0; Bt = d.B0; C = d.C0; ldc = 1536; n0 = bxs * 128;
        const int seg = n0 >> 9;
        bp = seg == 0 ? d.qb0 : (seg == 1 ? d.qb1 : d.qb2);
    } else {
        A = d.A1; Bt = d.B1; C = d.C1; ldc = 1024; n0 = (bxs - 12) * 128;
        bp = (n0 >> 9) ? d.cb1 : d.cb0;
    }
    const int K = 512;

    const int srow = lane >> 2;
    const int scol = (lane & 3) << 3;
    const u16* Ag0 = A  + (size_t)(m0 + w * 32 + srow) * K + scol;
    const u16* Ag1 = Ag0 + (size_t)16 * K;
    const u16* Bg0 = Bt + (size_t)(n0 + w * 32 + srow) * K + scol;
    const u16* Bg1 = Bg0 + (size_t)16 * K;
    const int ao0 = (w * 2 + 0) * 512;
    const int ao1 = (w * 2 + 1) * 512;

    f32x4 acc[4][4];
#pragma unroll
    for (int i = 0; i < 4; i++)
#pragma unroll
        for (int j = 0; j < 4; j++) { acc[i][j][0]=0.f; acc[i][j][1]=0.f; acc[i][j][2]=0.f; acc[i][j][3]=0.f; }

    gload16(Ag0, &As[0][ao0]);
    gload16(Ag1, &As[0][ao1]);
    gload16(Bg0, &Bs[0][ao0]);
    gload16(Bg1, &Bs[0][ao1]);
    __syncthreads();

    int cur = 0;
    for (int k0 = 0; k0 < K; k0 += 32) {
        if (k0 + 32 < K) {
            gload16(Ag0 + k0 + 32, &As[cur ^ 1][ao0]);
            gload16(Ag1 + k0 + 32, &As[cur ^ 1][ao1]);
            gload16(Bg0 + k0 + 32, &Bs[cur ^ 1][ao0]);
            gload16(Bg1 + k0 + 32, &Bs[cur ^ 1][ao1]);
        }
        short8 af[4], bf[4];
#pragma unroll
        for (int i = 0; i < 4; i++)
            af[i] = *(const short8*)&As[cur][(wr * 64 + i * 16 + c) * 32 + quad * 8];
#pragma unroll
        for (int j = 0; j < 4; j++)
            bf[j] = *(const short8*)&Bs[cur][(wc * 64 + j * 16 + c) * 32 + quad * 8];
#pragma unroll
        for (int i = 0; i < 4; i++)
#pragma unroll
            for (int j = 0; j < 4; j++)
                acc[i][j] = __builtin_amdgcn_mfma_f32_16x16x32_bf16(af[i], bf[j], acc[i][j], 0, 0, 0);
        __syncthreads();
        cur ^= 1;
    }

    const int nbase = n0 & 511;
    float bv[4];
#pragma unroll
    for (int j = 0; j < 4; j++) bv[j] = bp[nbase + wc * 64 + j * 16 + c];

#pragma unroll
    for (int i = 0; i < 4; i++) {
#pragma unroll
        for (int j = 0; j < 4; j++) {
            int colg = n0 + wc * 64 + j * 16 + c;
#pragma unroll
            for (int r = 0; r < 4; r++) {
                int rowg = m0 + wr * 64 + i * 16 + quad * 4 + r;
                C[(size_t)rowg * ldc + colg] = f2bf(acc[i][j][r] + bv[j]);
            }
        }
    }
}

// ---------------------------------------------------------------------------
// gemm64 v3: 128x64 tile, BK=32, 256 thr = 4 waves; single-barrier dbuf
//   + XCD swizzle. grid (8,64) = 512 = 8*64.
// ---------------------------------------------------------------------------
template<int OUT_BF16, int RELU>
__global__ __launch_bounds__(256) void gemm64(const u16* __restrict__ A,
                                              const u16* __restrict__ Bt,
                                              const float* __restrict__ bias,
                                              void* __restrict__ Cout,
                                              int M, int N, int K, int ldc)
{
    __shared__ u16 As[2][128 * 32];
    __shared__ u16 Bs[2][64 * 32];

    const int tid  = threadIdx.x;
    const int w    = tid >> 6;          // 0..3
    const int lane = tid & 63;
    const int c    = lane & 15;
    const int quad = lane >> 4;

    const int flat = xcd_flat();
    const int m0   = (flat / gridDim.x) * 128;
    const int n0   = (flat % gridDim.x) * 64;

    const int srow = lane >> 2;
    const int scol = (lane & 3) << 3;
    const u16* Ag0 = A  + (size_t)(m0 + w * 32 + srow) * K + scol;
    const u16* Ag1 = Ag0 + (size_t)16 * K;
    const u16* Bg  = Bt + (size_t)(n0 + w * 16 + srow) * K + scol;
    const int ao0 = (w * 2 + 0) * 512;
    const int ao1 = (w * 2 + 1) * 512;
    const int bo  = w * 512;

    f32x4 acc[2][4];
#pragma unroll
    for (int i = 0; i < 2; i++)
#pragma unroll
        for (int j = 0; j < 4; j++) { acc[i][j][0]=0.f; acc[i][j][1]=0.f; acc[i][j][2]=0.f; acc[i][j][3]=0.f; }

    gload16(Ag0, &As[0][ao0]);
    gload16(Ag1, &As[0][ao1]);
    gload16(Bg,  &Bs[0][bo]);
    __syncthreads();

    int cur = 0;
    for (int k0 = 0; k0 < K; k0 += 32) {
        if (k0 + 32 < K) {
            gload16(Ag0 + k0 + 32, &As[cur ^ 1][ao0]);
            gload16(Ag1 + k0 + 32, &As[cur ^ 1][ao1]);
            gload16(Bg  + k0 + 32, &Bs[cur ^ 1][bo]);
        }
        short8 af[2], bf[4];
#pragma unroll
        for (int i = 0; i < 2; i++)
            af[i] = *(const short8*)&As[cur][(w * 32 + i * 16 + c) * 32 + quad * 8];
#pragma unroll
        for (int j = 0; j < 4; j++)
            bf[j] = *(const short8*)&Bs[cur][(j * 16 + c) * 32 + quad * 8];
#pragma unroll
        for (int i = 0; i < 2; i++)
#pragma unroll
            for (int j = 0; j < 4; j++)
                acc[i][j] = __builtin_amdgcn_mfma_f32_16x16x32_bf16(af[i], bf[j], acc[i][j], 0, 0, 0);
        __syncthreads();
        cur ^= 1;
    }

    float bv[4];
#pragma unroll
    for (int j = 0; j < 4; j++) bv[j] = bias[n0 + j * 16 + c];

#pragma unroll
    for (int i = 0; i < 2; i++) {
#pragma unroll
        for (int j = 0; j < 4; j++) {
            int colg = n0 + j * 16 + c;
#pragma unroll
            for (int r = 0; r < 4; r++) {
                int rowg = m0 + w * 32 + i * 16 + quad * 4 + r;
                float v = acc[i][j][r] + bv[j];
                if (RELU) v = fmaxf(v, 0.f);
                if (OUT_BF16) ((u16*)Cout)[(size_t)rowg * ldc + colg] = f2bf(v);
                else          ((float*)Cout)[(size_t)rowg * ldc + colg] = v;
            }
        }
    }
}

// ---------------------------------------------------------------------------
// MFMA flash attention (v8/v10 config, measured best) + v15 CAUSAL BALANCE:
//   round-robin dispatch pairs block f with f+256 on one CU; under our
//   swizzle both get the SAME q-tile -> causal CUs carry 2..32 tile-units
//   (critical path ~1.9x mean). Fix: reverse q-tile order for bh-groups
//   2..3 within each XCD (idx bit 5), so the pair is (qt, 15-qt) = 17
//   units on every CU. Bijective; zero effect if the pairing assumption
//   is wrong; cross-attn identical (uniform work, flip is harmless).
//   Everything else unchanged: swapped QK^T (P in registers), 32 q/wave,
//   KVBLK=64 double-buffered (one barrier/tile), register prefetch,
//   cvt_pk P-pack, 72-u16 strides.
// No max-subtraction (|s|<~2): unnormalized O += P*V, l += sum(exp) ==
// reference softmax; p=0 == exp(-1e9) underflow.
// Layouts (m89/m91): A[m=lane&15][k=quad*8+j], B[k=quad*8+j][n=lane&15],
// C/D: col=lane&15, row=quad*4+reg. sigma(slot): qs=slot>>3, j=slot&7,
// key = (j<4 ? qs*4+j : 16+qs*4+j-4) (+32 second half); applied to both
// P-pack (A) and V^T staging (B) so it cancels.
// ---------------------------------------------------------------------------
template<bool CAUSAL>
__global__ __launch_bounds__(256) void attn_mfma(const u16* __restrict__ Q,
                                                 const u16* __restrict__ K,
                                                 const u16* __restrict__ V,
                                                 u16* __restrict__ O,
                                                 int ldq, int ldk, int ldv)
{
    __shared__ u16 Klds[2][64 * 72];       // [buf][key][dim], 144B rows
    __shared__ u16 Vtlds[2][64 * 72];      // [buf][dim][sigma-slot 0..63]

    const int tid  = threadIdx.x;
    const int w    = tid >> 6;
    const int lane = tid & 63;
    const int c    = lane & 15;
    const int quad = lane >> 4;

    const int flat = blockIdx.y * 16 + blockIdx.x;
    const int idx  = flat >> 3;
    const int bh   = (flat & 7) * 4 + (idx >> 4);
    int qt = idx & 15;
    if (CAUSAL && (idx & 32)) qt = 15 - qt;   // v15: balance (qt,15-qt) pairs
    const int q0   = qt * 128;

    const int b    = bh >> 3;
    const int h    = bh & 7;
    const int bS   = b * Sx;
    const int hoff = h * 64;
    const int qw   = q0 + w * 32;

    const int kkey = tid >> 3;
    const int kc8  = (tid & 7) << 3;
    const int vdim = tid & 63;
    const int vq   = tid >> 6;
    const int vp   = vq << 3;
    int vkey[8];
#pragma unroll
    for (int j = 0; j < 8; j++) vkey[j] = ((j & 4) << 2) + (vq << 2) + (j & 3);

    short8 qa[2][2];
#pragma unroll
    for (int a = 0; a < 2; a++) {
        const u16* qp = Q + (size_t)(bS + qw + a * 16 + c) * ldq + hoff;
        qa[a][0] = *(const short8*)(qp + quad * 8);
        qa[a][1] = *(const short8*)(qp + 32 + quad * 8);
    }

    f32x4 of[2][4];
#pragma unroll
    for (int a = 0; a < 2; a++)
#pragma unroll
        for (int f = 0; f < 4; f++) { of[a][f][0]=0.f; of[a][f][1]=0.f; of[a][f][2]=0.f; of[a][f][3]=0.f; }
    float lpart[2] = {0.f, 0.f};

    const int kend = CAUSAL ? (q0 + 128) : Sx;

    const u16* Kgp = K + (size_t)(bS + kkey) * ldk + hoff + kc8;
    const u16* Vgp = V + (size_t)bS * ldv + hoff + vdim;
    const size_t k32 = (size_t)32 * ldk;

    {
        short8 kr0 = *(const short8*)(Kgp);
        short8 kr1 = *(const short8*)(Kgp + k32);
        union { short8 v; u16 u[8]; } vb0, vb1;
#pragma unroll
        for (int j = 0; j < 8; j++) vb0.u[j] = Vgp[(size_t)vkey[j] * ldv];
#pragma unroll
        for (int j = 0; j < 8; j++) vb1.u[j] = Vgp[(size_t)(32 + vkey[j]) * ldv];
        *(short8*)&Klds[0][kkey * 72 + kc8]        = kr0;
        *(short8*)&Klds[0][(kkey + 32) * 72 + kc8] = kr1;
        *(short8*)&Vtlds[0][vdim * 72 + vp]        = vb0.v;
        *(short8*)&Vtlds[0][vdim * 72 + 32 + vp]   = vb1.v;
    }
    __syncthreads();

    int cur = 0;
    for (int kt = 0; kt < kend; kt += 64) {
        const bool more = (kt + 64 < kend);

        short8 kr0, kr1;
        union { short8 v; u16 u[8]; } vb0, vb1;
        if (more) {
            const u16* kp = Kgp + (size_t)(kt + 64) * ldk;
            kr0 = *(const short8*)(kp);
            kr1 = *(const short8*)(kp + k32);
#pragma unroll
            for (int j = 0; j < 8; j++)
                vb0.u[j] = Vgp[(size_t)(kt + 64 + vkey[j]) * ldv];
#pragma unroll
            for (int j = 0; j < 8; j++)
                vb1.u[j] = Vgp[(size_t)(kt + 96 + vkey[j]) * ldv];
        }

        int fm0 = 4, fm1 = 4;
        if (CAUSAL) {
            int d0 = ((qw + 15 - kt) >> 4) + 1;
            int d1 = ((qw + 31 - kt) >> 4) + 1;
            fm0 = d0 < 0 ? 0 : (d0 > 4 ? 4 : d0);
            fm1 = d1 < 0 ? 0 : (d1 > 4 ? 4 : d1);
        }

        if (fm1 > 0) {
            f32x4 s[2][4];
#pragma unroll
            for (int f = 0; f < 4; f++) {
                if (f < fm1) {
                    short8 kb0 = *(const short8*)&Klds[cur][(f * 16 + c) * 72 + quad * 8];
                    short8 kb1 = *(const short8*)&Klds[cur][(f * 16 + c) * 72 + 32 + quad * 8];
#pragma unroll
                    for (int a = 0; a < 2; a++) {
                        const int fma_ = a ? fm1 : fm0;
                        if (f < fma_) {
                            f32x4 z; z[0]=0.f; z[1]=0.f; z[2]=0.f; z[3]=0.f;
                            z = __builtin_amdgcn_mfma_f32_16x16x32_bf16(kb0, qa[a][0], z, 0, 0, 0);
                            z = __builtin_amdgcn_mfma_f32_16x16x32_bf16(kb1, qa[a][1], z, 0, 0, 0);
                            s[a][f] = z;
                        }
                    }
                }
            }

            union { unsigned int u[4]; short8 s8; } paA[2], paB[2];
#pragma unroll
            for (int a = 0; a < 2; a++) {
                const int fma_ = a ? fm1 : fm0;
                const int qg = qw + a * 16 + c;
#pragma unroll
                for (int f = 0; f < 4; f++) {
                    float p[4];
#pragma unroll
                    for (int r = 0; r < 4; r++) {
                        float pv = 0.f;
                        int kg = kt + f * 16 + quad * 4 + r;
                        if (f < fma_ && !(CAUSAL && kg > qg))
                            pv = __expf(s[a][f][r] * 0.125f);
                        p[r] = pv;
                    }
                    unsigned int w0 = cvt_pk_bf16(p[0], p[1]);
                    unsigned int w1 = cvt_pk_bf16(p[2], p[3]);
                    lpart[a] += __uint_as_float(w0 << 16) + __uint_as_float(w0 & 0xffff0000u);
                    lpart[a] += __uint_as_float(w1 << 16) + __uint_as_float(w1 & 0xffff0000u);
                    if (f < 2) { paA[a].u[f * 2] = w0; paA[a].u[f * 2 + 1] = w1; }
                    else       { paB[a].u[(f - 2) * 2] = w0; paB[a].u[(f - 2) * 2 + 1] = w1; }
                }
            }

#pragma unroll
            for (int f2 = 0; f2 < 4; f2++) {
                short8 vb0f = *(const short8*)&Vtlds[cur][(f2 * 16 + c) * 72 + quad * 8];
                short8 vb1f = *(const short8*)&Vtlds[cur][(f2 * 16 + c) * 72 + 32 + quad * 8];
                if (fm0 > 0)
                    of[0][f2] = __builtin_amdgcn_mfma_f32_16x16x32_bf16(paA[0].s8, vb0f, of[0][f2], 0, 0, 0);
                of[1][f2] = __builtin_amdgcn_mfma_f32_16x16x32_bf16(paA[1].s8, vb0f, of[1][f2], 0, 0, 0);
                if (fm0 > 2)
                    of[0][f2] = __builtin_amdgcn_mfma_f32_16x16x32_bf16(paB[0].s8, vb1f, of[0][f2], 0, 0, 0);
                if (fm1 > 2)
                    of[1][f2] = __builtin_amdgcn_mfma_f32_16x16x32_bf16(paB[1].s8, vb1f, of[1][f2], 0, 0, 0);
            }
        }

        if (more) {
            *(short8*)&Klds[cur ^ 1][kkey * 72 + kc8]        = kr0;
            *(short8*)&Klds[cur ^ 1][(kkey + 32) * 72 + kc8] = kr1;
            *(short8*)&Vtlds[cur ^ 1][vdim * 72 + vp]        = vb0.v;
            *(short8*)&Vtlds[cur ^ 1][vdim * 72 + 32 + vp]   = vb1.v;
        }
        __syncthreads();
        cur ^= 1;
    }

    float rinv[2][4];
#pragma unroll
    for (int a = 0; a < 2; a++) {
        float D = lpart[a];
        D += __shfl_xor(D, 16, 64);
        D += __shfl_xor(D, 32, 64);
        float rcp = 1.f / D;
#pragma unroll
        for (int r = 0; r < 4; r++)
            rinv[a][r] = __shfl(rcp, quad * 4 + r, 64);
    }

    u16* Ob = O + (size_t)(bS + qw) * Ex + hoff;
#pragma unroll
    for (int a = 0; a < 2; a++)
#pragma unroll
        for (int f = 0; f < 4; f++)
#pragma unroll
            for (int r = 0; r < 4; r++)
                Ob[(size_t)(a * 16 + quad * 4 + r) * Ex + f * 16 + c] =
                    f2bf(of[a][f][r] * rinv[a][r]);
}

// ---------------------------------------------------------------------------
// Fused residual-add + LayerNorm: one wave per row, 4 rows/block. (unchanged)
// ---------------------------------------------------------------------------
__global__ __launch_bounds__(256) void ln_add(const float* __restrict__ x,
                                              const float* __restrict__ s,
                                              const float* __restrict__ g,
                                              const float* __restrict__ bta,
                                              float* __restrict__ out,
                                              u16* __restrict__ out_bf)
{
    const int t    = threadIdx.x;
    const int w    = t >> 6;
    const int lane = t & 63;
    const int row  = blockIdx.x * 4 + w;
    const size_t base = (size_t)row * Ex + lane * 8;
    const int    gi   = lane * 8;

    float4 xv0 = *(const float4*)(x + base);
    float4 xv1 = *(const float4*)(x + base + 4);
    float4 sv0 = *(const float4*)(s + base);
    float4 sv1 = *(const float4*)(s + base + 4);
    float y[8] = { xv0.x + sv0.x, xv0.y + sv0.y, xv0.z + sv0.z, xv0.w + sv0.w,
                   xv1.x + sv1.x, xv1.y + sv1.y, xv1.z + sv1.z, xv1.w + sv1.w };

    float sum = 0.f, sq = 0.f;
#pragma unroll
    for (int i = 0; i < 8; i++) { sum += y[i]; sq += y[i] * y[i]; }
#pragma unroll
    for (int o = 1; o < 64; o <<= 1) {
        sum += __shfl_xor(sum, o, 64);
        sq  += __shfl_xor(sq,  o, 64);
    }

    const float mean = sum * (1.f / 512.f);
    const float var  = sq * (1.f / 512.f) - mean * mean;
    const float rstd = rsqrtf(var + 1e-3f);

    float4 gv0 = *(const float4*)(g + gi);
    float4 gv1 = *(const float4*)(g + gi + 4);
    float4 bv0 = *(const float4*)(bta + gi);
    float4 bv1 = *(const float4*)(bta + gi + 4);
    float gg[8] = { gv0.x, gv0.y, gv0.z, gv0.w, gv1.x, gv1.y, gv1.z, gv1.w };
    float bb[8] = { bv0.x, bv0.y, bv0.z, bv0.w, bv1.x, bv1.y, bv1.z, bv1.w };

    float o8[8];
#pragma unroll
    for (int i = 0; i < 8; i++) o8[i] = (y[i] - mean) * rstd * gg[i] + bb[i];

    *(float4*)(out + base)     = make_float4(o8[0], o8[1], o8[2], o8[3]);
    *(float4*)(out + base + 4) = make_float4(o8[4], o8[5], o8[6], o8[7]);
    if (out_bf) {
        union { short8 v; u16 u[8]; } ob;
#pragma unroll
        for (int i = 0; i < 8; i++) ob.u[i] = f2bf(o8[i]);
        *(short8*)(out_bf + base) = ob.v;
    }
}

// ---------------------------------------------------------------------------
// Orchestration (12 dispatches). 96 MB workspace (MB offsets):
//   [0,8) bw | [8,16) xb / P3 x2f=[8,24) | [16,24) encb
//   [24,48) qkvB | P2 qb=[24,32) | P3 ff1b=[24,56) | [48,56) ob
//   [56,72) projF | [72,88) x1f | [88,96) x1b/x2b
//   kvB -> d_out scratch (dead until ln3 writes it last).
// ---------------------------------------------------------------------------
extern "C" void kernel_launch(void* const* d_in, const int* in_sizes, int n_in,
                              void* d_out, int out_size, void* d_ws, size_t ws_size,
                              hipStream_t stream)
{
    const float* x     = (const float*)d_in[0];
    const float* enc   = (const float*)d_in[1];
    const float* sa_Wq = (const float*)d_in[4],  *sa_bq = (const float*)d_in[5];
    const float* sa_Wk = (const float*)d_in[6],  *sa_bk = (const float*)d_in[7];
    const float* sa_Wv = (const float*)d_in[8],  *sa_bv = (const float*)d_in[9];
    const float* sa_Wo = (const float*)d_in[10], *sa_bo = (const float*)d_in[11];
    const float* ca_Wq = (const float*)d_in[12], *ca_bq = (const float*)d_in[13];
    const float* ca_Wk = (const float*)d_in[14], *ca_bk = (const float*)d_in[15];
    const float* ca_Wv = (const float*)d_in[16], *ca_bv = (const float*)d_in[17];
    const float* ca_Wo = (const float*)d_in[18], *ca_bo = (const float*)d_in[19];
    const float* ff_W1 = (const float*)d_in[20], *ff_b1 = (const float*)d_in[21];
    const float* ff_W2 = (const float*)d_in[22], *ff_b2 = (const float*)d_in[23];
    const float* ln1_g = (const float*)d_in[24], *ln1_b = (const float*)d_in[25];
    const float* ln2_g = (const float*)d_in[26], *ln2_b = (const float*)d_in[27];
    const float* ln3_g = (const float*)d_in[28], *ln3_b = (const float*)d_in[29];

    char* ws = (char*)d_ws;
    const size_t MB = 1024 * 1024;
    u16*   bw   = (u16*)(ws);
    u16*   xb   = (u16*)(ws + 8  * MB);
    u16*   encb = (u16*)(ws + 16 * MB);
    u16*   qkvB = (u16*)(ws + 24 * MB);
    u16*   qb   = (u16*)(ws + 24 * MB);
    u16*   ff1b = (u16*)(ws + 24 * MB);
    u16*   ob   = (u16*)(ws + 48 * MB);
    float* projF= (float*)(ws + 56 * MB);
    float* x1f  = (float*)(ws + 72 * MB);
    u16*   x1b  = (u16*)(ws + 88 * MB);
    u16*   x2b  = (u16*)(ws + 88 * MB);
    float* x2f  = (float*)(ws + 8  * MB);
    u16*   kvB  = (u16*)d_out;          // 16 MB scratch; dead until ln3 writes

    u16* wsaq = bw;
    u16* wsao = bw + 786432;
    u16* wcaq = bw + 1048576;
    u16* wcak = bw + 1310720;
    u16* wcao = bw + 1835008;
    u16* wff1 = bw + 2097152;
    u16* wff2 = bw + 3145728;

    // ---- prepass: ONE dispatch ----
    PreArgs pa;
    pa.x = x; pa.enc = enc; pa.xb = xb; pa.encb = encb;
    pa.wp.w[0]=sa_Wq; pa.wp.w[1]=sa_Wk; pa.wp.w[2]=sa_Wv; pa.wp.w[3]=sa_Wo;
    pa.wp.w[4]=ca_Wq; pa.wp.w[5]=ca_Wk; pa.wp.w[6]=ca_Wv; pa.wp.w[7]=ca_Wo;
    pa.bw = bw; pa.ffW1 = ff_W1; pa.wff1 = wff1; pa.ffW2 = ff_W2; pa.wff2 = wff2;
    prepass<<<dim3(12288), dim3(256), 0, stream>>>(pa);

    auto G128 = [&](const u16* A, const u16* Wt, const float* b0, const float* b1,
                    const float* b2, const float* b3, void* C,
                    int N, int K, int ldc, int out_bf, int relu) {
        dim3 grid(N / 128, Tt / 128);
        if (out_bf) {
            if (relu) gemm128<1,1><<<grid, dim3(256), 0, stream>>>(A, Wt, b0,b1,b2,b3, C, Tt, N, K, ldc);
            else      gemm128<1,0><<<grid, dim3(256), 0, stream>>>(A, Wt, b0,b1,b2,b3, C, Tt, N, K, ldc);
        } else        gemm128<0,0><<<grid, dim3(256), 0, stream>>>(A, Wt, b0,b1,b2,b3, C, Tt, N, K, ldc);
    };
    auto G64 = [&](const u16* A, const u16* Wt, const float* bi, void* C,
                   int K, int ldc, int out_bf) {
        dim3 grid(512 / 64, Tt / 128);
        if (out_bf) gemm64<1,0><<<grid, dim3(256), 0, stream>>>(A, Wt, bi, C, Tt, 512, K, ldc);
        else        gemm64<0,0><<<grid, dim3(256), 0, stream>>>(A, Wt, bi, C, Tt, 512, K, ldc);
    };
    const dim3 agrid(Sx / 128, Bx * Hx);    // (16, 32) = 512 blocks
    const dim3 lgrid(Tt / 4);               // ln_add: 4 rows/block

    // ---- stage 1: fused QKV+caKV GEMM, self-attn, proj, add&norm ----
    DualArgs da;
    da.A0 = xb;   da.B0 = wsaq; da.C0 = qkvB;
    da.qb0 = sa_bq; da.qb1 = sa_bk; da.qb2 = sa_bv;
    da.A1 = encb; da.B1 = wcak; da.C1 = kvB;
    da.cb0 = ca_bk; da.cb1 = ca_bv;
    gemm128_dual<<<dim3(20, Tt / 128), dim3(256), 0, stream>>>(da);

    attn_mfma<true><<<agrid, dim3(256), 0, stream>>>(qkvB, qkvB + 512, qkvB + 1024,
                                                     ob, 1536, 1536, 1536);
    G64(ob, wsao, sa_bo, projF, 512, 512, 0);
    ln_add<<<lgrid, dim3(256), 0, stream>>>(x, projF, ln1_g, ln1_b, x1f, x1b);

    // ---- stage 2: cross-attention + add&norm (kvB already computed) ----
    G64(x1b, wcaq, ca_bq, qb, 512, 512, 1);
    attn_mfma<false><<<agrid, dim3(256), 0, stream>>>(qb, kvB, kvB + 512,
                                                      ob, 512, 1024, 1024);
    G64(ob, wcao, ca_bo, projF, 512, 512, 0);
    ln_add<<<lgrid, dim3(256), 0, stream>>>(x1f, projF, ln2_g, ln2_b, x2f, x2b);

    // ---- stage 3: FFN + add&norm ----
    G128(x2b, wff1, ff_b1, ff_b1 + 512, ff_b1 + 1024, ff_b1 + 1536,
         ff1b, 2048, 512, 2048, 1, 1);                       // ReLU
    G64(ff1b, wff2, ff_b2, projF, 2048, 512, 0);
    ln_add<<<lgrid, dim3(256), 0, stream>>>(x2f, projF, ln3_g, ln3_b,
                                            (float*)d_out, (u16*)nullptr);
}